// Round 3
// baseline (1448.430 us; speedup 1.0000x reference)
//
#include <hip/hip_runtime.h>
#include <hip/hip_bf16.h>
#include <math.h>

typedef __attribute__((ext_vector_type(8))) short short8;
typedef __attribute__((ext_vector_type(4))) float f32x4;

#define MAXFLAG 256
#define TAU 4e-6

__device__ inline ushort f2bf(float f) {
    __hip_bfloat16 h = __float2bfloat16(f);
    return *reinterpret_cast<ushort*>(&h);
}

// Split fp32 v into 3 bf16 terms (v = b0 + b1 + b2 to ~27 bits).
__device__ inline void split3_one(float v, ushort& h0, ushort& h1, ushort& h2) {
    __hip_bfloat16 b0 = __float2bfloat16(v);
    float f0 = __bfloat162float(b0);
    float r1 = v - f0;
    __hip_bfloat16 b1 = __float2bfloat16(r1);
    float f1 = __bfloat162float(b1);
    float r2 = r1 - f1;
    __hip_bfloat16 b2 = __float2bfloat16(r2);
    h0 = *reinterpret_cast<ushort*>(&b0);
    h1 = *reinterpret_cast<ushort*>(&b1);
    h2 = *reinterpret_cast<ushort*>(&b2);
}

// ---------------------------------------------------------------------------
// GEMM1 via 3-way bf16 split MFMA: C[8192,2048] = A[8192,1024] @ B[1024,2048]
// B pre-split/transposed into 3 bf16 planes [2048,1024]. fp32 accumulators.
// No LDS: fragments loaded directly from global (L1/L2-resident tiles).
// ---------------------------------------------------------------------------
__global__ __launch_bounds__(256)
void gemm1_split(const float* __restrict__ A, const ushort* __restrict__ Bt0,
                 const ushort* __restrict__ Bt1, const ushort* __restrict__ Bt2,
                 float* __restrict__ C)
{
    const int tid = threadIdx.x, wave = tid >> 6, lane = tid & 63;
    const int m0 = blockIdx.y * 128, n0 = blockIdx.x * 128;
    const int wm = (wave >> 1) * 64, wn = (wave & 1) * 64;
    const int lm = lane & 15, lk = (lane >> 4) * 8;

    f32x4 acc[4][4] = {};

    for (int k0 = 0; k0 < 1024; k0 += 32) {
        short8 fb0[4], fb1[4], fb2[4];
#pragma unroll
        for (int j = 0; j < 4; ++j) {
            size_t off = (size_t)(n0 + wn + j * 16 + lm) * 1024 + k0 + lk;
            fb0[j] = *(const short8*)(Bt0 + off);
            fb1[j] = *(const short8*)(Bt1 + off);
            fb2[j] = *(const short8*)(Bt2 + off);
        }
#pragma unroll
        for (int i = 0; i < 4; ++i) {
            const float* ap = A + (size_t)(m0 + wm + i * 16 + lm) * 1024 + k0 + lk;
            float av[8];
            *(float4*)(av)     = *(const float4*)(ap);
            *(float4*)(av + 4) = *(const float4*)(ap + 4);
            short8 a0, a1, a2;
#pragma unroll
            for (int e = 0; e < 8; ++e) {
                ushort h0, h1, h2;
                split3_one(av[e], h0, h1, h2);
                a0[e] = (short)h0; a1[e] = (short)h1; a2[e] = (short)h2;
            }
#pragma unroll
            for (int j = 0; j < 4; ++j) {
                acc[i][j] = __builtin_amdgcn_mfma_f32_16x16x32_bf16(a0, fb0[j], acc[i][j], 0, 0, 0);
                acc[i][j] = __builtin_amdgcn_mfma_f32_16x16x32_bf16(a0, fb1[j], acc[i][j], 0, 0, 0);
                acc[i][j] = __builtin_amdgcn_mfma_f32_16x16x32_bf16(a1, fb0[j], acc[i][j], 0, 0, 0);
                acc[i][j] = __builtin_amdgcn_mfma_f32_16x16x32_bf16(a0, fb2[j], acc[i][j], 0, 0, 0);
                acc[i][j] = __builtin_amdgcn_mfma_f32_16x16x32_bf16(a1, fb1[j], acc[i][j], 0, 0, 0);
                acc[i][j] = __builtin_amdgcn_mfma_f32_16x16x32_bf16(a2, fb0[j], acc[i][j], 0, 0, 0);
            }
        }
    }
#pragma unroll
    for (int i = 0; i < 4; ++i) {
        const int rowb = m0 + wm + i * 16 + (lane >> 4) * 4;
#pragma unroll
        for (int j = 0; j < 4; ++j) {
            const int col = n0 + wn + j * 16 + (lane & 15);
#pragma unroll
            for (int r = 0; r < 4; ++r)
                C[(size_t)(rowb + r) * 2048 + col] = acc[i][j][r];
        }
    }
}

// ---------------------------------------------------------------------------
// ge_inp_w [1024 k][2048 n] fp32 -> 3 bf16 split planes [2048 n][1024 k]
// ---------------------------------------------------------------------------
__global__ __launch_bounds__(256)
void split_bt_kernel(const float* __restrict__ B, ushort* __restrict__ t0,
                     ushort* __restrict__ t1, ushort* __restrict__ t2)
{
    __shared__ float tile[32][33];
    int bx = blockIdx.x, by = blockIdx.y;
    int t = threadIdx.x;
    int tr = t >> 5, tc = t & 31;
#pragma unroll
    for (int p = 0; p < 4; ++p)
        tile[tr + p * 8][tc] = B[(size_t)(by * 32 + tr + p * 8) * 2048 + bx * 32 + tc];
    __syncthreads();
#pragma unroll
    for (int p = 0; p < 4; ++p) {
        float v = tile[tc][tr + p * 8];
        ushort h0, h1, h2;
        split3_one(v, h0, h1, h2);
        size_t off = (size_t)(bx * 32 + tr + p * 8) * 1024 + by * 32 + tc;
        t0[off] = h0; t1[off] = h1; t2[off] = h2;
    }
}

// ---------------------------------------------------------------------------
// bf16 MFMA GEMM (m97 structure) — unchanged from R2 (verified).
// ---------------------------------------------------------------------------
__device__ inline void storeC(float v, float* p) { *p = v; }
__device__ inline void storeC(float v, __hip_bfloat16* p) { *p = __float2bfloat16(v); }

template <typename OutT>
__global__ __launch_bounds__(256)
void gemm_mfma_bt(const ushort* __restrict__ A, int lda,
                  const ushort* __restrict__ Bt,
                  OutT* __restrict__ C, int ldc, int K)
{
    __shared__ __attribute__((aligned(16))) ushort As[128 * 32];
    __shared__ __attribute__((aligned(16))) ushort Bs[128 * 32];
    const int tid = threadIdx.x;
    const int wave = tid >> 6, lane = tid & 63;
    const int m0 = blockIdx.y * 128, n0 = blockIdx.x * 128;
    const int wm = (wave >> 1) * 64, wn = (wave & 1) * 64;

    f32x4 acc[4][4] = {};

    const int r0 = (wave * 2 + 0) * 16 + (lane >> 2);
    const int r1 = (wave * 2 + 1) * 16 + (lane >> 2);
    const int kc = (lane & 3) * 8;

    for (int k0 = 0; k0 < K; k0 += 32) {
        const ushort* ga0 = A + (size_t)(m0 + r0) * lda + k0 + kc;
        const ushort* ga1 = A + (size_t)(m0 + r1) * lda + k0 + kc;
        const ushort* gb0 = Bt + (size_t)(n0 + r0) * K + k0 + kc;
        const ushort* gb1 = Bt + (size_t)(n0 + r1) * K + k0 + kc;
        __builtin_amdgcn_global_load_lds(
            (const __attribute__((address_space(1))) unsigned int*)ga0,
            (__attribute__((address_space(3))) unsigned int*)(As + (wave * 2 + 0) * 512),
            16, 0, 0);
        __builtin_amdgcn_global_load_lds(
            (const __attribute__((address_space(1))) unsigned int*)ga1,
            (__attribute__((address_space(3))) unsigned int*)(As + (wave * 2 + 1) * 512),
            16, 0, 0);
        __builtin_amdgcn_global_load_lds(
            (const __attribute__((address_space(1))) unsigned int*)gb0,
            (__attribute__((address_space(3))) unsigned int*)(Bs + (wave * 2 + 0) * 512),
            16, 0, 0);
        __builtin_amdgcn_global_load_lds(
            (const __attribute__((address_space(1))) unsigned int*)gb1,
            (__attribute__((address_space(3))) unsigned int*)(Bs + (wave * 2 + 1) * 512),
            16, 0, 0);
        __syncthreads();

        short8 af[4], bfr[4];
#pragma unroll
        for (int t = 0; t < 4; ++t) {
            af[t]  = *(const short8*)(As + (wm + t * 16 + (lane & 15)) * 32 + (lane >> 4) * 8);
            bfr[t] = *(const short8*)(Bs + (wn + t * 16 + (lane & 15)) * 32 + (lane >> 4) * 8);
        }
#pragma unroll
        for (int i = 0; i < 4; ++i)
#pragma unroll
            for (int j = 0; j < 4; ++j)
                acc[i][j] = __builtin_amdgcn_mfma_f32_16x16x32_bf16(af[i], bfr[j], acc[i][j], 0, 0, 0);
        __syncthreads();
    }

#pragma unroll
    for (int i = 0; i < 4; ++i) {
        const int rowb = m0 + wm + i * 16 + (lane >> 4) * 4;
#pragma unroll
        for (int j = 0; j < 4; ++j) {
            const int col = n0 + wn + j * 16 + (lane & 15);
#pragma unroll
            for (int r = 0; r < 4; ++r)
                storeC(acc[i][j][r], C + (size_t)(rowb + r) * ldc + col);
        }
    }
}

// ---------------------------------------------------------------------------
// conv width-3 + silu*silu, fp32 (fixup covers sign-critical tokens).
// ---------------------------------------------------------------------------
__global__ __launch_bounds__(256)
void conv_silu_kernel(const float* __restrict__ zg, const float* __restrict__ dw_w,
                      const float* __restrict__ dw_b, float* __restrict__ zm,
                      __hip_bfloat16* __restrict__ zmb)
{
    int idx = blockIdx.x * 256 + threadIdx.x;
    int d = idx & 1023;
    int t = idx >> 10;
    int n = t & 4095;
    const float* zrow = zg + (size_t)t * 2048;
    float z0 = (n > 0)    ? zg[(size_t)(t - 1) * 2048 + d] : 0.f;
    float z1 = zrow[d];
    float z2 = (n < 4095) ? zg[(size_t)(t + 1) * 2048 + d] : 0.f;
    float zc = z0 * dw_w[d * 3 + 0] + z1 * dw_w[d * 3 + 1] + z2 * dw_w[d * 3 + 2] + dw_b[d];
    float g  = zrow[1024 + d];
    float sc = zc / (1.f + expf(-zc));
    float sg = g  / (1.f + expf(-g));
    float r = sc * sg;
    zm[idx] = r;
    zmb[idx] = __float2bfloat16(r);
}

// ---------------------------------------------------------------------------
// Wb[j][h] = sum_m ge_out_w[j, m] * base_w[m, h]  (fp64; 1024x8)
// ---------------------------------------------------------------------------
__global__ __launch_bounds__(256)
void wb_kernel(const float* __restrict__ ge_out_w, const float* __restrict__ base_w,
               double* __restrict__ Wb)
{
    int e = blockIdx.x * 256 + threadIdx.x;
    int j = e >> 3, h = e & 7;
    const float* wr = ge_out_w + (size_t)j * 2048;
    double s = 0.0;
    for (int m = 0; m < 1024; ++m) s += (double)wr[m] * (double)base_w[m * 8 + h];
    Wb[e] = s;
}

// ---------------------------------------------------------------------------
__global__ __launch_bounds__(256)
void lowrank_kernel(const float* __restrict__ Aq, const float* __restrict__ Bq,
                    const float* __restrict__ Ak, const float* __restrict__ Bk,
                    const float* __restrict__ rand_gate,
                    float* __restrict__ Mq, float* __restrict__ Mkf)
{
    int t = threadIdx.x;
    for (int e = t; e < 4096; e += 256) {
        int j = e >> 6, d = e & 63;
        float s1 = 0.f, s2 = 0.f;
#pragma unroll
        for (int r = 0; r < 16; ++r) {
            s1 += Aq[j * 16 + r] * Bq[r * 64 + d];
            s2 += Ak[j * 16 + r] * Bk[r * 64 + d];
        }
        Mq[e] = s1;
        Mkf[e] = s2 * 0.5f * tanhf(1.0f + rand_gate[d]);
    }
}

__global__ void init_flag_kernel(int* flagcnt) { *flagcnt = 0; }

// ---------------------------------------------------------------------------
// LSH hash (fp64 from fp32 zm) + near-zero-sim flagging.
// ---------------------------------------------------------------------------
__global__ __launch_bounds__(256)
void hash_flag_kernel(const float* __restrict__ zm, const double* __restrict__ Wb,
                      const float* __restrict__ rot, const int* __restrict__ salts,
                      int* __restrict__ bids, int* __restrict__ flagcnt,
                      int* __restrict__ flagged)
{
    int wave = threadIdx.x >> 6, lane = threadIdx.x & 63;
    int t = blockIdx.x * 4 + wave;
    const float* zrow = zm + (size_t)t * 1024;
    double bacc[8] = {0, 0, 0, 0, 0, 0, 0, 0};
    for (int i = 0; i < 16; ++i) {
        int j = i * 64 + lane;
        double zv = (double)zrow[j];
        const double* wb = Wb + (size_t)j * 8;
#pragma unroll
        for (int h = 0; h < 8; ++h) bacc[h] += zv * wb[h];
    }
#pragma unroll
    for (int h = 0; h < 8; ++h) {
#pragma unroll
        for (int off = 32; off > 0; off >>= 1) bacc[h] += __shfl_xor(bacc[h], off);
    }
    if (lane < 32) {
        int r = lane >> 3, kk = lane & 7;
        double sim = 0.0;
#pragma unroll
        for (int h = 0; h < 8; ++h) sim += bacc[h] * (double)rot[(r * 8 + h) * 8 + kk];
        int m = (sim >= 0.0) ? salts[r * 8 + kk] : 0;
        m ^= __shfl_xor(m, 1);
        m ^= __shfl_xor(m, 2);
        m ^= __shfl_xor(m, 4);
        m ^= __shfl_xor(m, 8);
        m ^= __shfl_xor(m, 16);
        double as = fabs(sim);
#pragma unroll
        for (int off = 16; off > 0; off >>= 1) {
            double o = __shfl_xor(as, off);
            as = fmin(as, o);
        }
        if (lane == 0) {
            bids[t] = m & 31;
            if (as < TAU) {
                int slot = atomicAdd(flagcnt, 1);
                if (slot < MAXFLAG) flagged[slot] = t;
            }
        }
    }
}

// ---------------------------------------------------------------------------
// Exact fp64 recompute of bids for flagged tokens. One block per flagged slot.
// Replicates R1/R2 semantics: z = fp32-round(fp64 x@W); conv/silu fp64;
// zm = fp32 round; base/sim fp64.
// ---------------------------------------------------------------------------
__global__ __launch_bounds__(512)
void fixup_kernel(const float* __restrict__ x, const float* __restrict__ ge_inp_w,
                  const float* __restrict__ dw_w, const float* __restrict__ dw_b,
                  const double* __restrict__ Wb, const float* __restrict__ rot,
                  const int* __restrict__ salts, const int* __restrict__ flagcnt,
                  const int* __restrict__ flagged, int* __restrict__ bids)
{
    __shared__ float Lx[3 * 1024];   // x rows; first 1024 reused for zm after GEMV
    __shared__ float Lz[3 * 2048];   // z/gate rows (fp32-rounded)
    int cnt = *flagcnt; if (cnt > MAXFLAG) cnt = MAXFLAG;
    int s = blockIdx.x;
    if (s >= cnt) return;
    int t = flagged[s];
    int b = t >> 12, n = t & 4095;
    int tid = threadIdx.x;

    for (int idx = tid; idx < 3 * 1024; idx += 512) {
        int r = idx >> 10, d = idx & 1023;
        int row = n + r - 1;
        float v = 0.f;
        if (row >= 0 && row <= 4095) v = x[((size_t)(b * 4096 + row)) * 1024 + d];
        Lx[idx] = v;
    }
    __syncthreads();

    double acc[3][4] = {};
    for (int m = 0; m < 1024; ++m) {
        double x0 = (double)Lx[m];
        double x1 = (double)Lx[1024 + m];
        double x2 = (double)Lx[2048 + m];
        const float* wr = ge_inp_w + (size_t)m * 2048 + tid;
#pragma unroll
        for (int j = 0; j < 4; ++j) {
            double w = (double)wr[j * 512];
            acc[0][j] += x0 * w;
            acc[1][j] += x1 * w;
            acc[2][j] += x2 * w;
        }
    }
    __syncthreads();  // all Lx reads done before zm overlay
#pragma unroll
    for (int j = 0; j < 4; ++j)
#pragma unroll
        for (int r = 0; r < 3; ++r)
            Lz[r * 2048 + tid + j * 512] = (float)acc[r][j];
    __syncthreads();

    for (int d = tid; d < 1024; d += 512) {
        double z0 = (double)Lz[d];
        double z1 = (double)Lz[2048 + d];
        double z2 = (double)Lz[4096 + d];
        double zc = z0 * (double)dw_w[d * 3 + 0] + z1 * (double)dw_w[d * 3 + 1]
                  + z2 * (double)dw_w[d * 3 + 2] + (double)dw_b[d];
        double g  = (double)Lz[2048 + 1024 + d];
        double sc = zc / (1.0 + exp(-zc));
        double sg = g  / (1.0 + exp(-g));
        Lx[d] = (float)(sc * sg);
    }
    __syncthreads();

    if (tid < 64) {
        int lane = tid;
        double bacc[8] = {0, 0, 0, 0, 0, 0, 0, 0};
        for (int i = 0; i < 16; ++i) {
            int j = i * 64 + lane;
            double zv = (double)Lx[j];
            const double* wb = Wb + (size_t)j * 8;
#pragma unroll
            for (int h = 0; h < 8; ++h) bacc[h] += zv * wb[h];
        }
#pragma unroll
        for (int h = 0; h < 8; ++h) {
#pragma unroll
            for (int off = 32; off > 0; off >>= 1) bacc[h] += __shfl_xor(bacc[h], off);
        }
        if (lane < 32) {
            int r = lane >> 3, kk = lane & 7;
            double sim = 0.0;
#pragma unroll
            for (int h = 0; h < 8; ++h) sim += bacc[h] * (double)rot[(r * 8 + h) * 8 + kk];
            int m = (sim >= 0.0) ? salts[r * 8 + kk] : 0;
            m ^= __shfl_xor(m, 1);
            m ^= __shfl_xor(m, 2);
            m ^= __shfl_xor(m, 4);
            m ^= __shfl_xor(m, 8);
            m ^= __shfl_xor(m, 16);
            if (lane == 0) bids[t] = m & 31;
        }
    }
}

// ---------------------------------------------------------------------------
// Stable counting sort by bucket id. One block per batch.
// ---------------------------------------------------------------------------
__global__ __launch_bounds__(256)
void sort_kernel(const int* __restrict__ bids, int* __restrict__ order)
{
    __shared__ int counts[256 * 33];
    __shared__ int totals[32];
    __shared__ int bbase[32];
    int b = blockIdx.x, t = threadIdx.x;
    const int* bid = bids + b * 4096;
    int* ord = order + b * 4096;
    int* mycnt = counts + t * 33;
#pragma unroll
    for (int i = 0; i < 33; ++i) mycnt[i] = 0;
    int base_i = t * 16;
    int local[16];
#pragma unroll
    for (int i = 0; i < 16; ++i) {
        local[i] = bid[base_i + i];
        mycnt[local[i]]++;
    }
    __syncthreads();
    if (t < 32) {
        int run = 0;
        for (int c = 0; c < 256; ++c) {
            int v = counts[c * 33 + t];
            counts[c * 33 + t] = run;
            run += v;
        }
        totals[t] = run;
    }
    __syncthreads();
    if (t == 0) {
        int s = 0;
        for (int beta = 0; beta < 32; ++beta) { bbase[beta] = s; s += totals[beta]; }
    }
    __syncthreads();
#pragma unroll
    for (int i = 0; i < 16; ++i) {
        int bb = local[i];
        int pos = bbase[bb] + mycnt[bb];
        mycnt[bb]++;
        ord[pos] = base_i + i;
    }
}

// ---------------------------------------------------------------------------
// In-place per-64-row transform: X[r, :] = X[r, :] @ M  (64x64)
// ---------------------------------------------------------------------------
__global__ __launch_bounds__(256)
void rowmat64_kernel(float* __restrict__ X, const float* __restrict__ M)
{
    __shared__ float Xs[64][65];
    __shared__ __align__(16) float Ms[4096];
    int t = threadIdx.x;
    size_t row0 = (size_t)blockIdx.x * 64;
    {
        int r = t >> 2, cg = (t & 3) * 16;
        const float* xp = X + (row0 + r) * 64 + cg;
#pragma unroll
        for (int q = 0; q < 4; ++q) {
            float4 v = *(const float4*)(xp + q * 4);
            Xs[r][cg + q * 4 + 0] = v.x;
            Xs[r][cg + q * 4 + 1] = v.y;
            Xs[r][cg + q * 4 + 2] = v.z;
            Xs[r][cg + q * 4 + 3] = v.w;
        }
        const float* mp = M + t * 16;
#pragma unroll
        for (int q = 0; q < 4; ++q)
            *(float4*)(&Ms[t * 16 + q * 4]) = *(const float4*)(mp + q * 4);
    }
    __syncthreads();
    int c = t & 63, rg = (t >> 6) * 16;
    for (int rr = 0; rr < 16; ++rr) {
        int r = rg + rr;
        float acc = 0.f;
#pragma unroll
        for (int j = 0; j < 64; ++j) acc += Xs[r][j] * Ms[j * 64 + c];
        X[(row0 + r) * 64 + c] = acc;
    }
}

// ---------------------------------------------------------------------------
__global__ __launch_bounds__(256)
void pairmix_kernel(const float* __restrict__ kt0, float* __restrict__ ktm)
{
    int idx = blockIdx.x * 256 + threadIdx.x;
    int cfull = idx & 255;
    int t = idx >> 8;
    int p = t & 4095, b = t >> 12;
    int i = (p < 2048) ? p : (p - 2048);
    float sgn = (p < 2048) ? 1.f : -1.f;
    size_t r0 = ((size_t)(b * 4096 + 2 * i)) * 256 + cfull;
    ktm[idx] = kt0[r0] + sgn * kt0[r0 + 256];
}

// ---------------------------------------------------------------------------
__global__ __launch_bounds__(256)
void cast_bf16_kernel(const float4* __restrict__ in, ushort4* __restrict__ out)
{
    int i = blockIdx.x * 256 + threadIdx.x;
    float4 v = in[i];
    ushort4 o;
    o.x = f2bf(v.x); o.y = f2bf(v.y); o.z = f2bf(v.z); o.w = f2bf(v.w);
    out[i] = o;
}

// ---------------------------------------------------------------------------
__global__ __launch_bounds__(256)
void transpose_cast_kernel(const float* __restrict__ B, __hip_bfloat16* __restrict__ Bt,
                           int K, int N)
{
    __shared__ float tile[32][33];
    int bx = blockIdx.x, by = blockIdx.y;
    int t = threadIdx.x;
    int tr = t >> 5, tc = t & 31;
#pragma unroll
    for (int p = 0; p < 4; ++p)
        tile[tr + p * 8][tc] = B[(size_t)(by * 32 + tr + p * 8) * N + bx * 32 + tc];
    __syncthreads();
#pragma unroll
    for (int p = 0; p < 4; ++p)
        Bt[(size_t)(bx * 32 + tr + p * 8) * K + by * 32 + tc] =
            __float2bfloat16(tile[tc][tr + p * 8]);
}

// ---------------------------------------------------------------------------
// Bucketed attention; output bf16 (feeds final MFMA GEMM).
// ---------------------------------------------------------------------------
__global__ __launch_bounds__(256)
void attn_kernel(const float* __restrict__ qt, const float* __restrict__ ktm,
                 const float* __restrict__ v0, const int* __restrict__ order,
                 __hip_bfloat16* __restrict__ o_tok)
{
    __shared__ __align__(16) float Ks[128][64];
    __shared__ __align__(16) float Vs[128][64];
    const int c = blockIdx.x, h = blockIdx.y, b = blockIdx.z;
    const int t = threadIdx.x;
    const int r = t >> 1, hf = t & 1;
    const int kv = h >> 2;
    const int* ord = order + b * 4096 + c * 128;
    const int tokr = ord[r];
    const size_t rowr = (size_t)b * 4096 + tokr;
    {
        const float* kp = ktm + rowr * 256 + kv * 64 + hf * 32;
        const float* vp = v0 + rowr * 256 + kv * 64 + hf * 32;
#pragma unroll
        for (int q = 0; q < 8; ++q) {
            *(float4*)(&Ks[r][hf * 32 + q * 4]) = *(const float4*)(kp + q * 4);
            *(float4*)(&Vs[r][hf * 32 + q * 4]) = *(const float4*)(vp + q * 4);
        }
    }
    float4 qv[16];
    {
        const float* qp = qt + rowr * 1024 + h * 64;
#pragma unroll
        for (int q = 0; q < 16; ++q) qv[q] = *(const float4*)(qp + q * 4);
    }
    __syncthreads();

    float sc[64];
    float mx = -3.0e38f;
    for (int cc = 0; cc < 64; ++cc) {
        const int col = hf * 64 + cc;
        float sx = 0.f, sy = 0.f, sz = 0.f, sw = 0.f;
#pragma unroll
        for (int q = 0; q < 16; ++q) {
            const float4 k4 = *(const float4*)(&Ks[col][q * 4]);
            sx += qv[q].x * k4.x;
            sy += qv[q].y * k4.y;
            sz += qv[q].z * k4.z;
            sw += qv[q].w * k4.w;
        }
        const float s = (sx + sy + sz + sw) * 0.125f;
        sc[cc] = s;
        mx = fmaxf(mx, s);
    }
    mx = fmaxf(mx, __shfl_xor(mx, 1));
    float lsum = 0.f;
    for (int cc = 0; cc < 64; ++cc) {
        const float e = expf(sc[cc] - mx);
        sc[cc] = e;
        lsum += e;
    }
    lsum += __shfl_xor(lsum, 1);
    const float inv = 1.f / lsum;

    float acc[64];
#pragma unroll
    for (int d = 0; d < 64; ++d) acc[d] = 0.f;
    for (int j = 0; j < 64; ++j) {
        const float p = sc[j];
        const int row = hf * 64 + j;
#pragma unroll
        for (int d4 = 0; d4 < 16; ++d4) {
            const float4 v4 = *(const float4*)(&Vs[row][d4 * 4]);
            acc[d4 * 4 + 0] += p * v4.x;
            acc[d4 * 4 + 1] += p * v4.y;
            acc[d4 * 4 + 2] += p * v4.z;
            acc[d4 * 4 + 3] += p * v4.w;
        }
    }
#pragma unroll
    for (int d = 0; d < 64; ++d) acc[d] += __shfl_xor(acc[d], 1);

    __hip_bfloat16* op = o_tok + rowr * 1024 + h * 64 + hf * 32;
#pragma unroll
    for (int d = 0; d < 32; ++d)
        op[d] = __float2bfloat16(acc[hf * 32 + d] * inv);
}

// ---------------------------------------------------------------------------
extern "C" void kernel_launch(void* const* d_in, const int* in_sizes, int n_in,
                              void* d_out, int out_size, void* d_ws, size_t ws_size,
                              hipStream_t stream)
{
    const float* x         = (const float*)d_in[0];
    const float* ge_inp_w  = (const float*)d_in[1];
    const float* dw_w      = (const float*)d_in[2];
    const float* dw_b      = (const float*)d_in[3];
    const float* ge_out_w  = (const float*)d_in[4];
    const float* q_w       = (const float*)d_in[5];
    const float* k_w       = (const float*)d_in[6];
    const float* v_w       = (const float*)d_in[7];
    const float* Aq        = (const float*)d_in[8];
    const float* Bq        = (const float*)d_in[9];
    const float* Ak        = (const float*)d_in[10];
    const float* Bk        = (const float*)d_in[11];
    const float* rand_gate = (const float*)d_in[12];
    const float* base_w    = (const float*)d_in[13];
    const float* rot       = (const float*)d_in[14];
    const float* o_w       = (const float*)d_in[16];
    const int*   salts     = (const int*)d_in[17];

    char* ws = (char*)d_ws;
    // 0..64MB: zg fp32. After conv: qgkg_bf(0..32), x_bf/o_bf(32..48), Bt_*(48..~58)
    float*          zg       = (float*)(ws + 0);
    __hip_bfloat16* qgkg_bf  = (__hip_bfloat16*)(ws + 0);
    __hip_bfloat16* xo_bf    = (__hip_bfloat16*)(ws + 33554432);
    __hip_bfloat16* Bt_geout = (__hip_bfloat16*)(ws + 50331648);
    __hip_bfloat16* Bt_q     = (__hip_bfloat16*)(ws + 54525952);
    __hip_bfloat16* Bt_k     = (__hip_bfloat16*)(ws + 56623104);
    __hip_bfloat16* Bt_v     = (__hip_bfloat16*)(ws + 57147392);
    __hip_bfloat16* Bt_o     = (__hip_bfloat16*)(ws + 57671680);
    // 64..96MB: zm fp32 -> later q0
    float*          zm       = (float*)(ws + 67108864);
    float*          q0       = (float*)(ws + 67108864);
    // 96..112MB: Btsplit planes (pre-GEMM1) -> zm_bf -> k0/v0
    ushort*         Bts0     = (ushort*)(ws + 100663296);
    ushort*         Bts1     = (ushort*)(ws + 104857600);
    ushort*         Bts2     = (ushort*)(ws + 109051904);
    __hip_bfloat16* zm_bf    = (__hip_bfloat16*)(ws + 100663296);
    float*          k0       = (float*)(ws + 100663296);
    float*          v0       = (float*)(ws + 109051904);
    float*          ktm      = (float*)(ws + 117440512);
    float*          Mq       = (float*)(ws + 125829120);
    float*          Mkf      = (float*)(ws + 125845504);
    double*         Wb       = (double*)(ws + 125861888);
    int*            bids     = (int*)(ws + 125927424);
    int*            order    = (int*)(ws + 125960192);
    int*            flagcnt  = (int*)(ws + 125992960);
    int*            flagged  = (int*)(ws + 125993216);
    float*          outp     = (float*)d_out;

    // Precomputes
    init_flag_kernel<<<1, 1, 0, stream>>>(flagcnt);
    lowrank_kernel<<<1, 256, 0, stream>>>(Aq, Bq, Ak, Bk, rand_gate, Mq, Mkf);
    wb_kernel<<<32, 256, 0, stream>>>(ge_out_w, base_w, Wb);
    split_bt_kernel<<<dim3(64, 32), 256, 0, stream>>>(ge_inp_w, Bts0, Bts1, Bts2);

    // GEMM1 (3-way bf16-split MFMA): zg = x @ ge_inp_w  [8192x2048]
    gemm1_split<<<dim3(16, 64), 256, 0, stream>>>(x, Bts0, Bts1, Bts2, zg);
    // conv + silu*silu -> zm fp32 + zm_bf (overwrites dead Btsplit)
    conv_silu_kernel<<<32768, 256, 0, stream>>>(zg, dw_w, dw_b, zm, zm_bf);

    // Casts / weight transposes (zg dead now)
    cast_bf16_kernel<<<8192, 256, 0, stream>>>((const float4*)x, (ushort4*)xo_bf);
    transpose_cast_kernel<<<dim3(64, 32), 256, 0, stream>>>(ge_out_w, Bt_geout, 1024, 2048);
    transpose_cast_kernel<<<dim3(32, 32), 256, 0, stream>>>(q_w, Bt_q, 1024, 1024);
    transpose_cast_kernel<<<dim3(8, 32), 256, 0, stream>>>(k_w, Bt_k, 1024, 256);
    transpose_cast_kernel<<<dim3(8, 32), 256, 0, stream>>>(v_w, Bt_v, 1024, 256);
    transpose_cast_kernel<<<dim3(32, 32), 256, 0, stream>>>(o_w, Bt_o, 1024, 1024);

    // GEMM2 (bf16 MFMA): qgkg_bf = zm_bf @ ge_out_w  [8192x2048]
    gemm_mfma_bt<__hip_bfloat16><<<dim3(16, 64), 256, 0, stream>>>(
        (const ushort*)zm_bf, 1024, (const ushort*)Bt_geout, qgkg_bf, 2048, 1024);

    // hash + flag -> bids; exact fixup for near-zero sims; stable sort
    hash_flag_kernel<<<2048, 256, 0, stream>>>(zm, Wb, rot, salts, bids, flagcnt, flagged);
    fixup_kernel<<<MAXFLAG, 512, 0, stream>>>(x, ge_inp_w, dw_w, dw_b, Wb, rot, salts,
                                              flagcnt, flagged, bids);
    sort_kernel<<<2, 256, 0, stream>>>(bids, order);

    // q0 = qg @ q_w [8192x1024] (overwrites zm; hash done)
    gemm_mfma_bt<float><<<dim3(8, 64), 256, 0, stream>>>(
        (const ushort*)qgkg_bf, 2048, (const ushort*)Bt_q, q0, 1024, 1024);
    rowmat64_kernel<<<2048, 256, 0, stream>>>(q0, Mq);

    // k0 = kg @ k_w [8192x256] (overwrites zm_bf; GEMM2 + fixup done)
    gemm_mfma_bt<float><<<dim3(2, 64), 256, 0, stream>>>(
        (const ushort*)(qgkg_bf + 1024), 2048, (const ushort*)Bt_k, k0, 256, 1024);
    rowmat64_kernel<<<512, 256, 0, stream>>>(k0, Mkf);
    pairmix_kernel<<<8192, 256, 0, stream>>>(k0, ktm);

    // v0 = x @ v_w [8192x256]
    gemm_mfma_bt<float><<<dim3(2, 64), 256, 0, stream>>>(
        (const ushort*)xo_bf, 1024, (const ushort*)Bt_v, v0, 256, 1024);

    // bucketed attention -> o_bf (overwrites x_bf)
    attn_kernel<<<dim3(32, 16, 2), 256, 0, stream>>>(q0, ktm, v0, order, xo_bf);

    // final: out = o @ o_w [8192x1024]
    gemm_mfma_bt<float><<<dim3(8, 64), 256, 0, stream>>>(
        (const ushort*)xo_bf, 1024, (const ushort*)Bt_o, outp, 1024, 1024);
}

// Round 4
// 959.258 us; speedup vs baseline: 1.5099x; 1.5099x over previous
//
#include <hip/hip_runtime.h>
#include <hip/hip_bf16.h>
#include <math.h>

typedef __attribute__((ext_vector_type(8))) short short8;
typedef __attribute__((ext_vector_type(4))) float f32x4;

#define MAXFLAG 512
#define TAU 8e-6

__device__ inline ushort f2bf(float f) {
    __hip_bfloat16 h = __float2bfloat16(f);
    return *reinterpret_cast<ushort*>(&h);
}

// Split fp32 v into 2 bf16 terms (v = b0 + b1 + O(2^-18 v)).
__device__ inline void split2_one(float v, ushort& h0, ushort& h1) {
    __hip_bfloat16 b0 = __float2bfloat16(v);
    float f0 = __bfloat162float(b0);
    __hip_bfloat16 b1 = __float2bfloat16(v - f0);
    h0 = *reinterpret_cast<ushort*>(&b0);
    h1 = *reinterpret_cast<ushort*>(&b1);
}

// ---------------------------------------------------------------------------
// x [8192x1024] fp32 -> two bf16 planes (row-major, same layout)
// ---------------------------------------------------------------------------
__global__ __launch_bounds__(256)
void split_a_kernel(const float4* __restrict__ in, ushort4* __restrict__ o0,
                    ushort4* __restrict__ o1)
{
    int i = blockIdx.x * 256 + threadIdx.x;
    float4 v = in[i];
    ushort4 a, b;
    split2_one(v.x, a.x, b.x);
    split2_one(v.y, a.y, b.y);
    split2_one(v.z, a.z, b.z);
    split2_one(v.w, a.w, b.w);
    o0[i] = a;
    o1[i] = b;
}

// ---------------------------------------------------------------------------
// ge_inp_w [1024 k][2048 n] fp32 -> 2 bf16 split planes [2048 n][1024 k]
// ---------------------------------------------------------------------------
__global__ __launch_bounds__(256)
void split_bt2_kernel(const float* __restrict__ B, ushort* __restrict__ t0,
                      ushort* __restrict__ t1)
{
    __shared__ float tile[32][33];
    int bx = blockIdx.x, by = blockIdx.y;
    int t = threadIdx.x;
    int tr = t >> 5, tc = t & 31;
#pragma unroll
    for (int p = 0; p < 4; ++p)
        tile[tr + p * 8][tc] = B[(size_t)(by * 32 + tr + p * 8) * 2048 + bx * 32 + tc];
    __syncthreads();
#pragma unroll
    for (int p = 0; p < 4; ++p) {
        float v = tile[tc][tr + p * 8];
        ushort h0, h1;
        split2_one(v, h0, h1);
        size_t off = (size_t)(bx * 32 + tr + p * 8) * 1024 + by * 32 + tc;
        t0[off] = h0; t1[off] = h1;
    }
}

// ---------------------------------------------------------------------------
// GEMM1: C[8192,2048] = A @ B with 2-plane bf16 split on both operands.
// A0,A1: [8192,1024] bf16 row-major. B0t,B1t: [2048,1024] bf16 (n-major).
// m97 structure: 128x128 tile, BK=32, 4 LDS tiles, 48 MFMA / k-step
// (products a0b0 + a0b1 + a1b0; a1b1 ~2^-18 dropped, guarded by fixup tau).
// ---------------------------------------------------------------------------
__global__ __launch_bounds__(256)
void gemm1_mfma2(const ushort* __restrict__ A0, const ushort* __restrict__ A1,
                 const ushort* __restrict__ B0t, const ushort* __restrict__ B1t,
                 float* __restrict__ C)
{
    __shared__ __attribute__((aligned(16))) ushort As0[128 * 32];
    __shared__ __attribute__((aligned(16))) ushort As1[128 * 32];
    __shared__ __attribute__((aligned(16))) ushort Bs0[128 * 32];
    __shared__ __attribute__((aligned(16))) ushort Bs1[128 * 32];
    const int tid = threadIdx.x;
    const int wave = tid >> 6, lane = tid & 63;
    const int m0 = blockIdx.y * 128, n0 = blockIdx.x * 128;
    const int wm = (wave >> 1) * 64, wn = (wave & 1) * 64;

    f32x4 acc[4][4] = {};

    const int r0 = (wave * 2 + 0) * 16 + (lane >> 2);
    const int r1 = (wave * 2 + 1) * 16 + (lane >> 2);
    const int kc = (lane & 3) * 8;

    for (int k0 = 0; k0 < 1024; k0 += 32) {
        size_t ga0 = (size_t)(m0 + r0) * 1024 + k0 + kc;
        size_t ga1 = (size_t)(m0 + r1) * 1024 + k0 + kc;
        size_t gb0 = (size_t)(n0 + r0) * 1024 + k0 + kc;
        size_t gb1 = (size_t)(n0 + r1) * 1024 + k0 + kc;
        const int l0 = (wave * 2 + 0) * 512, l1 = (wave * 2 + 1) * 512;
        __builtin_amdgcn_global_load_lds(
            (const __attribute__((address_space(1))) unsigned int*)(A0 + ga0),
            (__attribute__((address_space(3))) unsigned int*)(As0 + l0), 16, 0, 0);
        __builtin_amdgcn_global_load_lds(
            (const __attribute__((address_space(1))) unsigned int*)(A0 + ga1),
            (__attribute__((address_space(3))) unsigned int*)(As0 + l1), 16, 0, 0);
        __builtin_amdgcn_global_load_lds(
            (const __attribute__((address_space(1))) unsigned int*)(A1 + ga0),
            (__attribute__((address_space(3))) unsigned int*)(As1 + l0), 16, 0, 0);
        __builtin_amdgcn_global_load_lds(
            (const __attribute__((address_space(1))) unsigned int*)(A1 + ga1),
            (__attribute__((address_space(3))) unsigned int*)(As1 + l1), 16, 0, 0);
        __builtin_amdgcn_global_load_lds(
            (const __attribute__((address_space(1))) unsigned int*)(B0t + gb0),
            (__attribute__((address_space(3))) unsigned int*)(Bs0 + l0), 16, 0, 0);
        __builtin_amdgcn_global_load_lds(
            (const __attribute__((address_space(1))) unsigned int*)(B0t + gb1),
            (__attribute__((address_space(3))) unsigned int*)(Bs0 + l1), 16, 0, 0);
        __builtin_amdgcn_global_load_lds(
            (const __attribute__((address_space(1))) unsigned int*)(B1t + gb0),
            (__attribute__((address_space(3))) unsigned int*)(Bs1 + l0), 16, 0, 0);
        __builtin_amdgcn_global_load_lds(
            (const __attribute__((address_space(1))) unsigned int*)(B1t + gb1),
            (__attribute__((address_space(3))) unsigned int*)(Bs1 + l1), 16, 0, 0);
        __syncthreads();

        short8 af0[4], af1[4], bf0[4], bf1[4];
#pragma unroll
        for (int t = 0; t < 4; ++t) {
            int aoff = (wm + t * 16 + (lane & 15)) * 32 + (lane >> 4) * 8;
            int boff = (wn + t * 16 + (lane & 15)) * 32 + (lane >> 4) * 8;
            af0[t] = *(const short8*)(As0 + aoff);
            af1[t] = *(const short8*)(As1 + aoff);
            bf0[t] = *(const short8*)(Bs0 + boff);
            bf1[t] = *(const short8*)(Bs1 + boff);
        }
#pragma unroll
        for (int i = 0; i < 4; ++i)
#pragma unroll
            for (int j = 0; j < 4; ++j) {
                acc[i][j] = __builtin_amdgcn_mfma_f32_16x16x32_bf16(af0[i], bf0[j], acc[i][j], 0, 0, 0);
                acc[i][j] = __builtin_amdgcn_mfma_f32_16x16x32_bf16(af0[i], bf1[j], acc[i][j], 0, 0, 0);
                acc[i][j] = __builtin_amdgcn_mfma_f32_16x16x32_bf16(af1[i], bf0[j], acc[i][j], 0, 0, 0);
            }
        __syncthreads();
    }
#pragma unroll
    for (int i = 0; i < 4; ++i) {
        const int rowb = m0 + wm + i * 16 + (lane >> 4) * 4;
#pragma unroll
        for (int j = 0; j < 4; ++j) {
            const int col = n0 + wn + j * 16 + (lane & 15);
#pragma unroll
            for (int r = 0; r < 4; ++r)
                C[(size_t)(rowb + r) * 2048 + col] = acc[i][j][r];
        }
    }
}

// ---------------------------------------------------------------------------
// bf16 MFMA GEMM (m97 structure) — verified R2/R3.
// ---------------------------------------------------------------------------
__device__ inline void storeC(float v, float* p) { *p = v; }
__device__ inline void storeC(float v, __hip_bfloat16* p) { *p = __float2bfloat16(v); }

template <typename OutT>
__global__ __launch_bounds__(256)
void gemm_mfma_bt(const ushort* __restrict__ A, int lda,
                  const ushort* __restrict__ Bt,
                  OutT* __restrict__ C, int ldc, int K)
{
    __shared__ __attribute__((aligned(16))) ushort As[128 * 32];
    __shared__ __attribute__((aligned(16))) ushort Bs[128 * 32];
    const int tid = threadIdx.x;
    const int wave = tid >> 6, lane = tid & 63;
    const int m0 = blockIdx.y * 128, n0 = blockIdx.x * 128;
    const int wm = (wave >> 1) * 64, wn = (wave & 1) * 64;

    f32x4 acc[4][4] = {};

    const int r0 = (wave * 2 + 0) * 16 + (lane >> 2);
    const int r1 = (wave * 2 + 1) * 16 + (lane >> 2);
    const int kc = (lane & 3) * 8;

    for (int k0 = 0; k0 < K; k0 += 32) {
        const ushort* ga0 = A + (size_t)(m0 + r0) * lda + k0 + kc;
        const ushort* ga1 = A + (size_t)(m0 + r1) * lda + k0 + kc;
        const ushort* gb0 = Bt + (size_t)(n0 + r0) * K + k0 + kc;
        const ushort* gb1 = Bt + (size_t)(n0 + r1) * K + k0 + kc;
        __builtin_amdgcn_global_load_lds(
            (const __attribute__((address_space(1))) unsigned int*)ga0,
            (__attribute__((address_space(3))) unsigned int*)(As + (wave * 2 + 0) * 512),
            16, 0, 0);
        __builtin_amdgcn_global_load_lds(
            (const __attribute__((address_space(1))) unsigned int*)ga1,
            (__attribute__((address_space(3))) unsigned int*)(As + (wave * 2 + 1) * 512),
            16, 0, 0);
        __builtin_amdgcn_global_load_lds(
            (const __attribute__((address_space(1))) unsigned int*)gb0,
            (__attribute__((address_space(3))) unsigned int*)(Bs + (wave * 2 + 0) * 512),
            16, 0, 0);
        __builtin_amdgcn_global_load_lds(
            (const __attribute__((address_space(1))) unsigned int*)gb1,
            (__attribute__((address_space(3))) unsigned int*)(Bs + (wave * 2 + 1) * 512),
            16, 0, 0);
        __syncthreads();

        short8 af[4], bfr[4];
#pragma unroll
        for (int t = 0; t < 4; ++t) {
            af[t]  = *(const short8*)(As + (wm + t * 16 + (lane & 15)) * 32 + (lane >> 4) * 8);
            bfr[t] = *(const short8*)(Bs + (wn + t * 16 + (lane & 15)) * 32 + (lane >> 4) * 8);
        }
#pragma unroll
        for (int i = 0; i < 4; ++i)
#pragma unroll
            for (int j = 0; j < 4; ++j)
                acc[i][j] = __builtin_amdgcn_mfma_f32_16x16x32_bf16(af[i], bfr[j], acc[i][j], 0, 0, 0);
        __syncthreads();
    }

#pragma unroll
    for (int i = 0; i < 4; ++i) {
        const int rowb = m0 + wm + i * 16 + (lane >> 4) * 4;
#pragma unroll
        for (int j = 0; j < 4; ++j) {
            const int col = n0 + wn + j * 16 + (lane & 15);
#pragma unroll
            for (int r = 0; r < 4; ++r)
                storeC(acc[i][j][r], C + (size_t)(rowb + r) * ldc + col);
        }
    }
}

// ---------------------------------------------------------------------------
// conv width-3 + silu*silu, fp32 (fixup covers sign-critical tokens).
// ---------------------------------------------------------------------------
__global__ __launch_bounds__(256)
void conv_silu_kernel(const float* __restrict__ zg, const float* __restrict__ dw_w,
                      const float* __restrict__ dw_b, float* __restrict__ zm,
                      __hip_bfloat16* __restrict__ zmb)
{
    int idx = blockIdx.x * 256 + threadIdx.x;
    int d = idx & 1023;
    int t = idx >> 10;
    int n = t & 4095;
    const float* zrow = zg + (size_t)t * 2048;
    float z0 = (n > 0)    ? zg[(size_t)(t - 1) * 2048 + d] : 0.f;
    float z1 = zrow[d];
    float z2 = (n < 4095) ? zg[(size_t)(t + 1) * 2048 + d] : 0.f;
    float zc = z0 * dw_w[d * 3 + 0] + z1 * dw_w[d * 3 + 1] + z2 * dw_w[d * 3 + 2] + dw_b[d];
    float g  = zrow[1024 + d];
    float sc = zc / (1.f + expf(-zc));
    float sg = g  / (1.f + expf(-g));
    float r = sc * sg;
    zm[idx] = r;
    zmb[idx] = __float2bfloat16(r);
}

// ---------------------------------------------------------------------------
// Wb[j][h] = sum_m ge_out_w[j, m] * base_w[m, h]  (fp64; 1024x8)
// ---------------------------------------------------------------------------
__global__ __launch_bounds__(256)
void wb_kernel(const float* __restrict__ ge_out_w, const float* __restrict__ base_w,
               double* __restrict__ Wb)
{
    int e = blockIdx.x * 256 + threadIdx.x;
    int j = e >> 3, h = e & 7;
    const float* wr = ge_out_w + (size_t)j * 2048;
    double s = 0.0;
    for (int m = 0; m < 1024; ++m) s += (double)wr[m] * (double)base_w[m * 8 + h];
    Wb[e] = s;
}

// ---------------------------------------------------------------------------
__global__ __launch_bounds__(256)
void lowrank_kernel(const float* __restrict__ Aq, const float* __restrict__ Bq,
                    const float* __restrict__ Ak, const float* __restrict__ Bk,
                    const float* __restrict__ rand_gate,
                    float* __restrict__ Mq, float* __restrict__ Mkf)
{
    int t = threadIdx.x;
    for (int e = t; e < 4096; e += 256) {
        int j = e >> 6, d = e & 63;
        float s1 = 0.f, s2 = 0.f;
#pragma unroll
        for (int r = 0; r < 16; ++r) {
            s1 += Aq[j * 16 + r] * Bq[r * 64 + d];
            s2 += Ak[j * 16 + r] * Bk[r * 64 + d];
        }
        Mq[e] = s1;
        Mkf[e] = s2 * 0.5f * tanhf(1.0f + rand_gate[d]);
    }
}

__global__ void init_flag_kernel(int* flagcnt) { *flagcnt = 0; }

// ---------------------------------------------------------------------------
// LSH hash (fp64 from fp32 zm) + near-zero-sim flagging.
// ---------------------------------------------------------------------------
__global__ __launch_bounds__(256)
void hash_flag_kernel(const float* __restrict__ zm, const double* __restrict__ Wb,
                      const float* __restrict__ rot, const int* __restrict__ salts,
                      int* __restrict__ bids, int* __restrict__ flagcnt,
                      int* __restrict__ flagged)
{
    int wave = threadIdx.x >> 6, lane = threadIdx.x & 63;
    int t = blockIdx.x * 4 + wave;
    const float* zrow = zm + (size_t)t * 1024;
    double bacc[8] = {0, 0, 0, 0, 0, 0, 0, 0};
    for (int i = 0; i < 16; ++i) {
        int j = i * 64 + lane;
        double zv = (double)zrow[j];
        const double* wb = Wb + (size_t)j * 8;
#pragma unroll
        for (int h = 0; h < 8; ++h) bacc[h] += zv * wb[h];
    }
#pragma unroll
    for (int h = 0; h < 8; ++h) {
#pragma unroll
        for (int off = 32; off > 0; off >>= 1) bacc[h] += __shfl_xor(bacc[h], off);
    }
    if (lane < 32) {
        int r = lane >> 3, kk = lane & 7;
        double sim = 0.0;
#pragma unroll
        for (int h = 0; h < 8; ++h) sim += bacc[h] * (double)rot[(r * 8 + h) * 8 + kk];
        int m = (sim >= 0.0) ? salts[r * 8 + kk] : 0;
        m ^= __shfl_xor(m, 1);
        m ^= __shfl_xor(m, 2);
        m ^= __shfl_xor(m, 4);
        m ^= __shfl_xor(m, 8);
        m ^= __shfl_xor(m, 16);
        double as = fabs(sim);
#pragma unroll
        for (int off = 16; off > 0; off >>= 1) {
            double o = __shfl_xor(as, off);
            as = fmin(as, o);
        }
        if (lane == 0) {
            bids[t] = m & 31;
            if (as < TAU) {
                int slot = atomicAdd(flagcnt, 1);
                if (slot < MAXFLAG) flagged[slot] = t;
            }
        }
    }
}

// ---------------------------------------------------------------------------
// Exact fp64 recompute of bids for flagged tokens. One block per slot.
// v2: coalesced float4 weight loads; only 4096 needed outputs
// (3 z-rows cols 0..1023 + row-n gate cols 1024..2047).
// Threads 0..255 (waves 0-3): z cols; threads 256..511 (waves 4-7): gate cols.
// ---------------------------------------------------------------------------
__global__ __launch_bounds__(512)
void fixup_kernel(const float* __restrict__ x, const float* __restrict__ ge_inp_w,
                  const float* __restrict__ dw_w, const float* __restrict__ dw_b,
                  const double* __restrict__ Wb, const float* __restrict__ rot,
                  const int* __restrict__ salts, const int* __restrict__ flagcnt,
                  const int* __restrict__ flagged, int* __restrict__ bids)
{
    __shared__ float Lx[3 * 1024];
    __shared__ float Lz[3 * 1024];
    __shared__ float Lg[1024];
    int cnt = *flagcnt; if (cnt > MAXFLAG) cnt = MAXFLAG;
    int s = blockIdx.x;
    if (s >= cnt) return;
    int t = flagged[s];
    int b = t >> 12, n = t & 4095;
    int tid = threadIdx.x;

    for (int idx = tid; idx < 3 * 1024; idx += 512) {
        int r = idx >> 10, d = idx & 1023;
        int row = n + r - 1;
        float v = 0.f;
        if (row >= 0 && row <= 4095) v = x[((size_t)(b * 4096 + row)) * 1024 + d];
        Lx[idx] = v;
    }
    __syncthreads();

    const bool isz = tid < 256;
    const int col = isz ? tid * 4 : 1024 + (tid - 256) * 4;
    const float* wp = ge_inp_w + col;

    double a00 = 0, a01 = 0, a02 = 0, a03 = 0;   // row n-1 (or gate row n)
    double a10 = 0, a11 = 0, a12 = 0, a13 = 0;   // row n
    double a20 = 0, a21 = 0, a22 = 0, a23 = 0;   // row n+1

    for (int m = 0; m < 1024; m += 4) {
        float4 w0 = *(const float4*)(wp + (size_t)(m + 0) * 2048);
        float4 w1 = *(const float4*)(wp + (size_t)(m + 1) * 2048);
        float4 w2 = *(const float4*)(wp + (size_t)(m + 2) * 2048);
        float4 w3 = *(const float4*)(wp + (size_t)(m + 3) * 2048);
        if (isz) {
#pragma unroll
            for (int u = 0; u < 4; ++u) {
                float4 w = (u == 0) ? w0 : (u == 1) ? w1 : (u == 2) ? w2 : w3;
                double x0 = (double)Lx[m + u];
                double x1 = (double)Lx[1024 + m + u];
                double x2 = (double)Lx[2048 + m + u];
                a00 += x0 * (double)w.x; a01 += x0 * (double)w.y;
                a02 += x0 * (double)w.z; a03 += x0 * (double)w.w;
                a10 += x1 * (double)w.x; a11 += x1 * (double)w.y;
                a12 += x1 * (double)w.z; a13 += x1 * (double)w.w;
                a20 += x2 * (double)w.x; a21 += x2 * (double)w.y;
                a22 += x2 * (double)w.z; a23 += x2 * (double)w.w;
            }
        } else {
#pragma unroll
            for (int u = 0; u < 4; ++u) {
                float4 w = (u == 0) ? w0 : (u == 1) ? w1 : (u == 2) ? w2 : w3;
                double xg = (double)Lx[1024 + m + u];
                a00 += xg * (double)w.x; a01 += xg * (double)w.y;
                a02 += xg * (double)w.z; a03 += xg * (double)w.w;
            }
        }
    }

    if (isz) {
        int c = tid * 4;
        Lz[c + 0] = (float)a00; Lz[c + 1] = (float)a01;
        Lz[c + 2] = (float)a02; Lz[c + 3] = (float)a03;
        Lz[1024 + c + 0] = (float)a10; Lz[1024 + c + 1] = (float)a11;
        Lz[1024 + c + 2] = (float)a12; Lz[1024 + c + 3] = (float)a13;
        Lz[2048 + c + 0] = (float)a20; Lz[2048 + c + 1] = (float)a21;
        Lz[2048 + c + 2] = (float)a22; Lz[2048 + c + 3] = (float)a23;
    } else {
        int c = (tid - 256) * 4;
        Lg[c + 0] = (float)a00; Lg[c + 1] = (float)a01;
        Lg[c + 2] = (float)a02; Lg[c + 3] = (float)a03;
    }
    __syncthreads();

    for (int d = tid; d < 1024; d += 512) {
        double z0 = (double)Lz[d];
        double z1 = (double)Lz[1024 + d];
        double z2 = (double)Lz[2048 + d];
        double zc = z0 * (double)dw_w[d * 3 + 0] + z1 * (double)dw_w[d * 3 + 1]
                  + z2 * (double)dw_w[d * 3 + 2] + (double)dw_b[d];
        double g  = (double)Lg[d];
        double sc = zc / (1.0 + exp(-zc));
        double sg = g  / (1.0 + exp(-g));
        Lx[d] = (float)(sc * sg);
    }
    __syncthreads();

    if (tid < 64) {
        int lane = tid;
        double bacc[8] = {0, 0, 0, 0, 0, 0, 0, 0};
        for (int i = 0; i < 16; ++i) {
            int j = i * 64 + lane;
            double zv = (double)Lx[j];
            const double* wb = Wb + (size_t)j * 8;
#pragma unroll
            for (int h = 0; h < 8; ++h) bacc[h] += zv * wb[h];
        }
#pragma unroll
        for (int h = 0; h < 8; ++h) {
#pragma unroll
            for (int off = 32; off > 0; off >>= 1) bacc[h] += __shfl_xor(bacc[h], off);
        }
        if (lane < 32) {
            int r = lane >> 3, kk = lane & 7;
            double sim = 0.0;
#pragma unroll
            for (int h = 0; h < 8; ++h) sim += bacc[h] * (double)rot[(r * 8 + h) * 8 + kk];
            int m = (sim >= 0.0) ? salts[r * 8 + kk] : 0;
            m ^= __shfl_xor(m, 1);
            m ^= __shfl_xor(m, 2);
            m ^= __shfl_xor(m, 4);
            m ^= __shfl_xor(m, 8);
            m ^= __shfl_xor(m, 16);
            if (lane == 0) bids[t] = m & 31;
        }
    }
}

// ---------------------------------------------------------------------------
// Stable counting sort by bucket id. One block per batch.
// ---------------------------------------------------------------------------
__global__ __launch_bounds__(256)
void sort_kernel(const int* __restrict__ bids, int* __restrict__ order)
{
    __shared__ int counts[256 * 33];
    __shared__ int totals[32];
    __shared__ int bbase[32];
    int b = blockIdx.x, t = threadIdx.x;
    const int* bid = bids + b * 4096;
    int* ord = order + b * 4096;
    int* mycnt = counts + t * 33;
#pragma unroll
    for (int i = 0; i < 33; ++i) mycnt[i] = 0;
    int base_i = t * 16;
    int local[16];
#pragma unroll
    for (int i = 0; i < 16; ++i) {
        local[i] = bid[base_i + i];
        mycnt[local[i]]++;
    }
    __syncthreads();
    if (t < 32) {
        int run = 0;
        for (int c = 0; c < 256; ++c) {
            int v = counts[c * 33 + t];
            counts[c * 33 + t] = run;
            run += v;
        }
        totals[t] = run;
    }
    __syncthreads();
    if (t == 0) {
        int s = 0;
        for (int beta = 0; beta < 32; ++beta) { bbase[beta] = s; s += totals[beta]; }
    }
    __syncthreads();
#pragma unroll
    for (int i = 0; i < 16; ++i) {
        int bb = local[i];
        int pos = bbase[bb] + mycnt[bb];
        mycnt[bb]++;
        ord[pos] = base_i + i;
    }
}

// ---------------------------------------------------------------------------
// In-place per-64-row transform: X[r, :] = X[r, :] @ M  (64x64)
// ---------------------------------------------------------------------------
__global__ __launch_bounds__(256)
void rowmat64_kernel(float* __restrict__ X, const float* __restrict__ M)
{
    __shared__ float Xs[64][65];
    __shared__ __align__(16) float Ms[4096];
    int t = threadIdx.x;
    size_t row0 = (size_t)blockIdx.x * 64;
    {
        int r = t >> 2, cg = (t & 3) * 16;
        const float* xp = X + (row0 + r) * 64 + cg;
#pragma unroll
        for (int q = 0; q < 4; ++q) {
            float4 v = *(const float4*)(xp + q * 4);
            Xs[r][cg + q * 4 + 0] = v.x;
            Xs[r][cg + q * 4 + 1] = v.y;
            Xs[r][cg + q * 4 + 2] = v.z;
            Xs[r][cg + q * 4 + 3] = v.w;
        }
        const float* mp = M + t * 16;
#pragma unroll
        for (int q = 0; q < 4; ++q)
            *(float4*)(&Ms[t * 16 + q * 4]) = *(const float4*)(mp + q * 4);
    }
    __syncthreads();
    int c = t & 63, rg = (t >> 6) * 16;
    for (int rr = 0; rr < 16; ++rr) {
        int r = rg + rr;
        float acc = 0.f;
#pragma unroll
        for (int j = 0; j < 64; ++j) acc += Xs[r][j] * Ms[j * 64 + c];
        X[(row0 + r) * 64 + c] = acc;
    }
}

// ---------------------------------------------------------------------------
__global__ __launch_bounds__(256)
void pairmix_kernel(const float* __restrict__ kt0, float* __restrict__ ktm)
{
    int idx = blockIdx.x * 256 + threadIdx.x;
    int cfull = idx & 255;
    int t = idx >> 8;
    int p = t & 4095, b = t >> 12;
    int i = (p < 2048) ? p : (p - 2048);
    float sgn = (p < 2048) ? 1.f : -1.f;
    size_t r0 = ((size_t)(b * 4096 + 2 * i)) * 256 + cfull;
    ktm[idx] = kt0[r0] + sgn * kt0[r0 + 256];
}

// ---------------------------------------------------------------------------
__global__ __launch_bounds__(256)
void cast_bf16_kernel(const float4* __restrict__ in, ushort4* __restrict__ out)
{
    int i = blockIdx.x * 256 + threadIdx.x;
    float4 v = in[i];
    ushort4 o;
    o.x = f2bf(v.x); o.y = f2bf(v.y); o.z = f2bf(v.z); o.w = f2bf(v.w);
    out[i] = o;
}

// ---------------------------------------------------------------------------
__global__ __launch_bounds__(256)
void transpose_cast_kernel(const float* __restrict__ B, __hip_bfloat16* __restrict__ Bt,
                           int K, int N)
{
    __shared__ float tile[32][33];
    int bx = blockIdx.x, by = blockIdx.y;
    int t = threadIdx.x;
    int tr = t >> 5, tc = t & 31;
#pragma unroll
    for (int p = 0; p < 4; ++p)
        tile[tr + p * 8][tc] = B[(size_t)(by * 32 + tr + p * 8) * N + bx * 32 + tc];
    __syncthreads();
#pragma unroll
    for (int p = 0; p < 4; ++p)
        Bt[(size_t)(bx * 32 + tr + p * 8) * K + by * 32 + tc] =
            __float2bfloat16(tile[tc][tr + p * 8]);
}

// ---------------------------------------------------------------------------
// Bucketed attention; output bf16 (feeds final MFMA GEMM).
// ---------------------------------------------------------------------------
__global__ __launch_bounds__(256)
void attn_kernel(const float* __restrict__ qt, const float* __restrict__ ktm,
                 const float* __restrict__ v0, const int* __restrict__ order,
                 __hip_bfloat16* __restrict__ o_tok)
{
    __shared__ __align__(16) float Ks[128][64];
    __shared__ __align__(16) float Vs[128][64];
    const int c = blockIdx.x, h = blockIdx.y, b = blockIdx.z;
    const int t = threadIdx.x;
    const int r = t >> 1, hf = t & 1;
    const int kv = h >> 2;
    const int* ord = order + b * 4096 + c * 128;
    const int tokr = ord[r];
    const size_t rowr = (size_t)b * 4096 + tokr;
    {
        const float* kp = ktm + rowr * 256 + kv * 64 + hf * 32;
        const float* vp = v0 + rowr * 256 + kv * 64 + hf * 32;
#pragma unroll
        for (int q = 0; q < 8; ++q) {
            *(float4*)(&Ks[r][hf * 32 + q * 4]) = *(const float4*)(kp + q * 4);
            *(float4*)(&Vs[r][hf * 32 + q * 4]) = *(const float4*)(vp + q * 4);
        }
    }
    float4 qv[16];
    {
        const float* qp = qt + rowr * 1024 + h * 64;
#pragma unroll
        for (int q = 0; q < 16; ++q) qv[q] = *(const float4*)(qp + q * 4);
    }
    __syncthreads();

    float sc[64];
    float mx = -3.0e38f;
    for (int cc = 0; cc < 64; ++cc) {
        const int col = hf * 64 + cc;
        float sx = 0.f, sy = 0.f, sz = 0.f, sw = 0.f;
#pragma unroll
        for (int q = 0; q < 16; ++q) {
            const float4 k4 = *(const float4*)(&Ks[col][q * 4]);
            sx += qv[q].x * k4.x;
            sy += qv[q].y * k4.y;
            sz += qv[q].z * k4.z;
            sw += qv[q].w * k4.w;
        }
        const float s = (sx + sy + sz + sw) * 0.125f;
        sc[cc] = s;
        mx = fmaxf(mx, s);
    }
    mx = fmaxf(mx, __shfl_xor(mx, 1));
    float lsum = 0.f;
    for (int cc = 0; cc < 64; ++cc) {
        const float e = expf(sc[cc] - mx);
        sc[cc] = e;
        lsum += e;
    }
    lsum += __shfl_xor(lsum, 1);
    const float inv = 1.f / lsum;

    float acc[64];
#pragma unroll
    for (int d = 0; d < 64; ++d) acc[d] = 0.f;
    for (int j = 0; j < 64; ++j) {
        const float p = sc[j];
        const int row = hf * 64 + j;
#pragma unroll
        for (int d4 = 0; d4 < 16; ++d4) {
            const float4 v4 = *(const float4*)(&Vs[row][d4 * 4]);
            acc[d4 * 4 + 0] += p * v4.x;
            acc[d4 * 4 + 1] += p * v4.y;
            acc[d4 * 4 + 2] += p * v4.z;
            acc[d4 * 4 + 3] += p * v4.w;
        }
    }
#pragma unroll
    for (int d = 0; d < 64; ++d) acc[d] += __shfl_xor(acc[d], 1);

    __hip_bfloat16* op = o_tok + rowr * 1024 + h * 64 + hf * 32;
#pragma unroll
    for (int d = 0; d < 32; ++d)
        op[d] = __float2bfloat16(acc[hf * 32 + d] * inv);
}

// ---------------------------------------------------------------------------
extern "C" void kernel_launch(void* const* d_in, const int* in_sizes, int n_in,
                              void* d_out, int out_size, void* d_ws, size_t ws_size,
                              hipStream_t stream)
{
    const float* x         = (const float*)d_in[0];
    const float* ge_inp_w  = (const float*)d_in[1];
    const float* dw_w      = (const float*)d_in[2];
    const float* dw_b      = (const float*)d_in[3];
    const float* ge_out_w  = (const float*)d_in[4];
    const float* q_w       = (const float*)d_in[5];
    const float* k_w       = (const float*)d_in[6];
    const float* v_w       = (const float*)d_in[7];
    const float* Aq        = (const float*)d_in[8];
    const float* Bq        = (const float*)d_in[9];
    const float* Ak        = (const float*)d_in[10];
    const float* Bk        = (const float*)d_in[11];
    const float* rand_gate = (const float*)d_in[12];
    const float* base_w    = (const float*)d_in[13];
    const float* rot       = (const float*)d_in[14];
    const float* o_w       = (const float*)d_in[16];
    const int*   salts     = (const int*)d_in[17];

    char* ws = (char*)d_ws;
    // 0..64MB: zg fp32. After conv: qgkg_bf(0..32), x_bf/o_bf(32..48), Bt_*(48..~58)
    float*          zg       = (float*)(ws + 0);
    __hip_bfloat16* qgkg_bf  = (__hip_bfloat16*)(ws + 0);
    __hip_bfloat16* xo_bf    = (__hip_bfloat16*)(ws + 33554432);
    __hip_bfloat16* Bt_geout = (__hip_bfloat16*)(ws + 50331648);
    __hip_bfloat16* Bt_q     = (__hip_bfloat16*)(ws + 54525952);
    __hip_bfloat16* Bt_k     = (__hip_bfloat16*)(ws + 56623104);
    __hip_bfloat16* Bt_v     = (__hip_bfloat16*)(ws + 57147392);
    __hip_bfloat16* Bt_o     = (__hip_bfloat16*)(ws + 57671680);
    // 64..96MB: A0/A1 bf16 planes (pre-conv) -> zm fp32 -> q0
    ushort*         A0p      = (ushort*)(ws + 67108864);   // 16MB
    ushort*         A1p      = (ushort*)(ws + 83886080);   // 16MB
    float*          zm       = (float*)(ws + 67108864);
    float*          q0       = (float*)(ws + 67108864);
    // 96..112MB: B0t/B1t planes (pre-conv) -> zm_bf -> k0/v0
    ushort*         B0tp     = (ushort*)(ws + 100663296);  // 4MB
    ushort*         B1tp     = (ushort*)(ws + 104857600);  // 4MB
    __hip_bfloat16* zm_bf    = (__hip_bfloat16*)(ws + 100663296);
    float*          k0       = (float*)(ws + 100663296);
    float*          v0       = (float*)(ws + 109051904);
    float*          ktm      = (float*)(ws + 117440512);
    float*          Mq       = (float*)(ws + 125829120);
    float*          Mkf      = (float*)(ws + 125845504);
    double*         Wb       = (double*)(ws + 125861888);
    int*            bids     = (int*)(ws + 125927424);
    int*            order    = (int*)(ws + 125960192);
    int*            flagcnt  = (int*)(ws + 125992960);
    int*            flagged  = (int*)(ws + 125993216);
    float*          outp     = (float*)d_out;

    // Precomputes
    init_flag_kernel<<<1, 1, 0, stream>>>(flagcnt);
    lowrank_kernel<<<1, 256, 0, stream>>>(Aq, Bq, Ak, Bk, rand_gate, Mq, Mkf);
    wb_kernel<<<32, 256, 0, stream>>>(ge_out_w, base_w, Wb);
    split_a_kernel<<<8192, 256, 0, stream>>>((const float4*)x, (ushort4*)A0p, (ushort4*)A1p);
    split_bt2_kernel<<<dim3(64, 32), 256, 0, stream>>>(ge_inp_w, B0tp, B1tp);

    // GEMM1 (2-plane bf16-split MFMA): zg = x @ ge_inp_w  [8192x2048]
    gemm1_mfma2<<<dim3(16, 64), 256, 0, stream>>>(A0p, A1p, B0tp, B1tp, zg);
    // conv + silu*silu -> zm fp32 (over A0/A1) + zm_bf (over B0t/B1t)
    conv_silu_kernel<<<32768, 256, 0, stream>>>(zg, dw_w, dw_b, zm, zm_bf);

    // Casts / weight transposes (zg dead now)
    cast_bf16_kernel<<<8192, 256, 0, stream>>>((const float4*)x, (ushort4*)xo_bf);
    transpose_cast_kernel<<<dim3(64, 32), 256, 0, stream>>>(ge_out_w, Bt_geout, 1024, 2048);
    transpose_cast_kernel<<<dim3(32, 32), 256, 0, stream>>>(q_w, Bt_q, 1024, 1024);
    transpose_cast_kernel<<<dim3(8, 32), 256, 0, stream>>>(k_w, Bt_k, 1024, 256);
    transpose_cast_kernel<<<dim3(8, 32), 256, 0, stream>>>(v_w, Bt_v, 1024, 256);
    transpose_cast_kernel<<<dim3(32, 32), 256, 0, stream>>>(o_w, Bt_o, 1024, 1024);

    // GEMM2 (bf16 MFMA): qgkg_bf = zm_bf @ ge_out_w  [8192x2048]
    gemm_mfma_bt<__hip_bfloat16><<<dim3(16, 64), 256, 0, stream>>>(
        (const ushort*)zm_bf, 1024, (const ushort*)Bt_geout, qgkg_bf, 2048, 1024);

    // hash + flag -> bids; exact fixup for near-zero sims; stable sort
    hash_flag_kernel<<<2048, 256, 0, stream>>>(zm, Wb, rot, salts, bids, flagcnt, flagged);
    fixup_kernel<<<MAXFLAG, 512, 0, stream>>>(x, ge_inp_w, dw_w, dw_b, Wb, rot, salts,
                                              flagcnt, flagged, bids);
    sort_kernel<<<2, 256, 0, stream>>>(bids, order);

    // q0 = qg @ q_w [8192x1024] (overwrites zm; hash done)
    gemm_mfma_bt<float><<<dim3(8, 64), 256, 0, stream>>>(
        (const ushort*)qgkg_bf, 2048, (const ushort*)Bt_q, q0, 1024, 1024);
    rowmat64_kernel<<<2048, 256, 0, stream>>>(q0, Mq);

    // k0 = kg @ k_w [8192x256] (overwrites zm_bf; GEMM2 + fixup done)
    gemm_mfma_bt<float><<<dim3(2, 64), 256, 0, stream>>>(
        (const ushort*)(qgkg_bf + 1024), 2048, (const ushort*)Bt_k, k0, 256, 1024);
    rowmat64_kernel<<<512, 256, 0, stream>>>(k0, Mkf);
    pairmix_kernel<<<8192, 256, 0, stream>>>(k0, ktm);

    // v0 = x @ v_w [8192x256]
    gemm_mfma_bt<float><<<dim3(2, 64), 256, 0, stream>>>(
        (const ushort*)xo_bf, 1024, (const ushort*)Bt_v, v0, 256, 1024);

    // bucketed attention -> o_bf (overwrites x_bf)
    attn_kernel<<<dim3(32, 16, 2), 256, 0, stream>>>(q0, ktm, v0, order, xo_bf);

    // final: out = o @ o_w [8192x1024]
    gemm_mfma_bt<float><<<dim3(8, 64), 256, 0, stream>>>(
        (const ushort*)xo_bf, 1024, (const ushort*)Bt_o, outp, 1024, 1024);
}

// Round 5
// 936.381 us; speedup vs baseline: 1.5468x; 1.0244x over previous
//
#include <hip/hip_runtime.h>
#include <hip/hip_bf16.h>
#include <math.h>

typedef __attribute__((ext_vector_type(8))) short short8;
typedef __attribute__((ext_vector_type(4))) float f32x4;

#define MAXFLAG 512
#define TAU 8e-6

__device__ inline ushort f2bf(float f) {
    __hip_bfloat16 h = __float2bfloat16(f);
    return *reinterpret_cast<ushort*>(&h);
}

// Split fp32 v into 2 bf16 terms (v = b0 + b1 + O(2^-18 v)).
__device__ inline void split2_one(float v, ushort& h0, ushort& h1) {
    __hip_bfloat16 b0 = __float2bfloat16(v);
    float f0 = __bfloat162float(b0);
    __hip_bfloat16 b1 = __float2bfloat16(v - f0);
    h0 = *reinterpret_cast<ushort*>(&b0);
    h1 = *reinterpret_cast<ushort*>(&b1);
}

// ---------------------------------------------------------------------------
// x [8192x1024] fp32 -> two bf16 planes (row-major, same layout)
// ---------------------------------------------------------------------------
__global__ __launch_bounds__(256)
void split_a_kernel(const float4* __restrict__ in, ushort4* __restrict__ o0,
                    ushort4* __restrict__ o1)
{
    int i = blockIdx.x * 256 + threadIdx.x;
    float4 v = in[i];
    ushort4 a, b;
    split2_one(v.x, a.x, b.x);
    split2_one(v.y, a.y, b.y);
    split2_one(v.z, a.z, b.z);
    split2_one(v.w, a.w, b.w);
    o0[i] = a;
    o1[i] = b;
}

// ---------------------------------------------------------------------------
// ge_inp_w [1024 k][2048 n] fp32 -> 2 bf16 split planes [2048 n][1024 k]
// ---------------------------------------------------------------------------
__global__ __launch_bounds__(256)
void split_bt2_kernel(const float* __restrict__ B, ushort* __restrict__ t0,
                      ushort* __restrict__ t1)
{
    __shared__ float tile[32][33];
    int bx = blockIdx.x, by = blockIdx.y;
    int t = threadIdx.x;
    int tr = t >> 5, tc = t & 31;
#pragma unroll
    for (int p = 0; p < 4; ++p)
        tile[tr + p * 8][tc] = B[(size_t)(by * 32 + tr + p * 8) * 2048 + bx * 32 + tc];
    __syncthreads();
#pragma unroll
    for (int p = 0; p < 4; ++p) {
        float v = tile[tc][tr + p * 8];
        ushort h0, h1;
        split2_one(v, h0, h1);
        size_t off = (size_t)(bx * 32 + tr + p * 8) * 1024 + by * 32 + tc;
        t0[off] = h0; t1[off] = h1;
    }
}

// ---------------------------------------------------------------------------
// GEMM1: C[8192,2048] = A @ B with 2-plane bf16 split on both operands.
// ---------------------------------------------------------------------------
__global__ __launch_bounds__(256)
void gemm1_mfma2(const ushort* __restrict__ A0, const ushort* __restrict__ A1,
                 const ushort* __restrict__ B0t, const ushort* __restrict__ B1t,
                 float* __restrict__ C)
{
    __shared__ __attribute__((aligned(16))) ushort As0[128 * 32];
    __shared__ __attribute__((aligned(16))) ushort As1[128 * 32];
    __shared__ __attribute__((aligned(16))) ushort Bs0[128 * 32];
    __shared__ __attribute__((aligned(16))) ushort Bs1[128 * 32];
    const int tid = threadIdx.x;
    const int wave = tid >> 6, lane = tid & 63;
    const int m0 = blockIdx.y * 128, n0 = blockIdx.x * 128;
    const int wm = (wave >> 1) * 64, wn = (wave & 1) * 64;

    f32x4 acc[4][4] = {};

    const int r0 = (wave * 2 + 0) * 16 + (lane >> 2);
    const int r1 = (wave * 2 + 1) * 16 + (lane >> 2);
    const int kc = (lane & 3) * 8;

    for (int k0 = 0; k0 < 1024; k0 += 32) {
        size_t ga0 = (size_t)(m0 + r0) * 1024 + k0 + kc;
        size_t ga1 = (size_t)(m0 + r1) * 1024 + k0 + kc;
        size_t gb0 = (size_t)(n0 + r0) * 1024 + k0 + kc;
        size_t gb1 = (size_t)(n0 + r1) * 1024 + k0 + kc;
        const int l0 = (wave * 2 + 0) * 512, l1 = (wave * 2 + 1) * 512;
        __builtin_amdgcn_global_load_lds(
            (const __attribute__((address_space(1))) unsigned int*)(A0 + ga0),
            (__attribute__((address_space(3))) unsigned int*)(As0 + l0), 16, 0, 0);
        __builtin_amdgcn_global_load_lds(
            (const __attribute__((address_space(1))) unsigned int*)(A0 + ga1),
            (__attribute__((address_space(3))) unsigned int*)(As0 + l1), 16, 0, 0);
        __builtin_amdgcn_global_load_lds(
            (const __attribute__((address_space(1))) unsigned int*)(A1 + ga0),
            (__attribute__((address_space(3))) unsigned int*)(As1 + l0), 16, 0, 0);
        __builtin_amdgcn_global_load_lds(
            (const __attribute__((address_space(1))) unsigned int*)(A1 + ga1),
            (__attribute__((address_space(3))) unsigned int*)(As1 + l1), 16, 0, 0);
        __builtin_amdgcn_global_load_lds(
            (const __attribute__((address_space(1))) unsigned int*)(B0t + gb0),
            (__attribute__((address_space(3))) unsigned int*)(Bs0 + l0), 16, 0, 0);
        __builtin_amdgcn_global_load_lds(
            (const __attribute__((address_space(1))) unsigned int*)(B0t + gb1),
            (__attribute__((address_space(3))) unsigned int*)(Bs0 + l1), 16, 0, 0);
        __builtin_amdgcn_global_load_lds(
            (const __attribute__((address_space(1))) unsigned int*)(B1t + gb0),
            (__attribute__((address_space(3))) unsigned int*)(Bs1 + l0), 16, 0, 0);
        __builtin_amdgcn_global_load_lds(
            (const __attribute__((address_space(1))) unsigned int*)(B1t + gb1),
            (__attribute__((address_space(3))) unsigned int*)(Bs1 + l1), 16, 0, 0);
        __syncthreads();

        short8 af0[4], af1[4], bf0[4], bf1[4];
#pragma unroll
        for (int t = 0; t < 4; ++t) {
            int aoff = (wm + t * 16 + (lane & 15)) * 32 + (lane >> 4) * 8;
            int boff = (wn + t * 16 + (lane & 15)) * 32 + (lane >> 4) * 8;
            af0[t] = *(const short8*)(As0 + aoff);
            af1[t] = *(const short8*)(As1 + aoff);
            bf0[t] = *(const short8*)(Bs0 + boff);
            bf1[t] = *(const short8*)(Bs1 + boff);
        }
#pragma unroll
        for (int i = 0; i < 4; ++i)
#pragma unroll
            for (int j = 0; j < 4; ++j) {
                acc[i][j] = __builtin_amdgcn_mfma_f32_16x16x32_bf16(af0[i], bf0[j], acc[i][j], 0, 0, 0);
                acc[i][j] = __builtin_amdgcn_mfma_f32_16x16x32_bf16(af0[i], bf1[j], acc[i][j], 0, 0, 0);
                acc[i][j] = __builtin_amdgcn_mfma_f32_16x16x32_bf16(af1[i], bf0[j], acc[i][j], 0, 0, 0);
            }
        __syncthreads();
    }
#pragma unroll
    for (int i = 0; i < 4; ++i) {
        const int rowb = m0 + wm + i * 16 + (lane >> 4) * 4;
#pragma unroll
        for (int j = 0; j < 4; ++j) {
            const int col = n0 + wn + j * 16 + (lane & 15);
#pragma unroll
            for (int r = 0; r < 4; ++r)
                C[(size_t)(rowb + r) * 2048 + col] = acc[i][j][r];
        }
    }
}

// ---------------------------------------------------------------------------
// bf16 MFMA GEMM (m97 structure) — verified R2-R4.
// ---------------------------------------------------------------------------
__device__ inline void storeC(float v, float* p) { *p = v; }
__device__ inline void storeC(float v, __hip_bfloat16* p) { *p = __float2bfloat16(v); }

template <typename OutT>
__global__ __launch_bounds__(256)
void gemm_mfma_bt(const ushort* __restrict__ A, int lda,
                  const ushort* __restrict__ Bt,
                  OutT* __restrict__ C, int ldc, int K)
{
    __shared__ __attribute__((aligned(16))) ushort As[128 * 32];
    __shared__ __attribute__((aligned(16))) ushort Bs[128 * 32];
    const int tid = threadIdx.x;
    const int wave = tid >> 6, lane = tid & 63;
    const int m0 = blockIdx.y * 128, n0 = blockIdx.x * 128;
    const int wm = (wave >> 1) * 64, wn = (wave & 1) * 64;

    f32x4 acc[4][4] = {};

    const int r0 = (wave * 2 + 0) * 16 + (lane >> 2);
    const int r1 = (wave * 2 + 1) * 16 + (lane >> 2);
    const int kc = (lane & 3) * 8;

    for (int k0 = 0; k0 < K; k0 += 32) {
        const ushort* ga0 = A + (size_t)(m0 + r0) * lda + k0 + kc;
        const ushort* ga1 = A + (size_t)(m0 + r1) * lda + k0 + kc;
        const ushort* gb0 = Bt + (size_t)(n0 + r0) * K + k0 + kc;
        const ushort* gb1 = Bt + (size_t)(n0 + r1) * K + k0 + kc;
        __builtin_amdgcn_global_load_lds(
            (const __attribute__((address_space(1))) unsigned int*)ga0,
            (__attribute__((address_space(3))) unsigned int*)(As + (wave * 2 + 0) * 512),
            16, 0, 0);
        __builtin_amdgcn_global_load_lds(
            (const __attribute__((address_space(1))) unsigned int*)ga1,
            (__attribute__((address_space(3))) unsigned int*)(As + (wave * 2 + 1) * 512),
            16, 0, 0);
        __builtin_amdgcn_global_load_lds(
            (const __attribute__((address_space(1))) unsigned int*)gb0,
            (__attribute__((address_space(3))) unsigned int*)(Bs + (wave * 2 + 0) * 512),
            16, 0, 0);
        __builtin_amdgcn_global_load_lds(
            (const __attribute__((address_space(1))) unsigned int*)gb1,
            (__attribute__((address_space(3))) unsigned int*)(Bs + (wave * 2 + 1) * 512),
            16, 0, 0);
        __syncthreads();

        short8 af[4], bfr[4];
#pragma unroll
        for (int t = 0; t < 4; ++t) {
            af[t]  = *(const short8*)(As + (wm + t * 16 + (lane & 15)) * 32 + (lane >> 4) * 8);
            bfr[t] = *(const short8*)(Bs + (wn + t * 16 + (lane & 15)) * 32 + (lane >> 4) * 8);
        }
#pragma unroll
        for (int i = 0; i < 4; ++i)
#pragma unroll
            for (int j = 0; j < 4; ++j)
                acc[i][j] = __builtin_amdgcn_mfma_f32_16x16x32_bf16(af[i], bfr[j], acc[i][j], 0, 0, 0);
        __syncthreads();
    }

#pragma unroll
    for (int i = 0; i < 4; ++i) {
        const int rowb = m0 + wm + i * 16 + (lane >> 4) * 4;
#pragma unroll
        for (int j = 0; j < 4; ++j) {
            const int col = n0 + wn + j * 16 + (lane & 15);
#pragma unroll
            for (int r = 0; r < 4; ++r)
                storeC(acc[i][j][r], C + (size_t)(rowb + r) * ldc + col);
        }
    }
}

// ---------------------------------------------------------------------------
// conv width-3 + silu*silu, fp32 (fixup covers sign-critical tokens).
// ---------------------------------------------------------------------------
__global__ __launch_bounds__(256)
void conv_silu_kernel(const float* __restrict__ zg, const float* __restrict__ dw_w,
                      const float* __restrict__ dw_b, float* __restrict__ zm,
                      __hip_bfloat16* __restrict__ zmb)
{
    int idx = blockIdx.x * 256 + threadIdx.x;
    int d = idx & 1023;
    int t = idx >> 10;
    int n = t & 4095;
    const float* zrow = zg + (size_t)t * 2048;
    float z0 = (n > 0)    ? zg[(size_t)(t - 1) * 2048 + d] : 0.f;
    float z1 = zrow[d];
    float z2 = (n < 4095) ? zg[(size_t)(t + 1) * 2048 + d] : 0.f;
    float zc = z0 * dw_w[d * 3 + 0] + z1 * dw_w[d * 3 + 1] + z2 * dw_w[d * 3 + 2] + dw_b[d];
    float g  = zrow[1024 + d];
    float sc = zc / (1.f + expf(-zc));
    float sg = g  / (1.f + expf(-g));
    float r = sc * sg;
    zm[idx] = r;
    zmb[idx] = __float2bfloat16(r);
}

// ---------------------------------------------------------------------------
// Wb[j][h] = sum_m ge_out_w[j, m] * base_w[m, h]  (fp64; 1024x8)
// ---------------------------------------------------------------------------
__global__ __launch_bounds__(256)
void wb_kernel(const float* __restrict__ ge_out_w, const float* __restrict__ base_w,
               double* __restrict__ Wb)
{
    int e = blockIdx.x * 256 + threadIdx.x;
    int j = e >> 3, h = e & 7;
    const float* wr = ge_out_w + (size_t)j * 2048;
    double s = 0.0;
    for (int m = 0; m < 1024; ++m) s += (double)wr[m] * (double)base_w[m * 8 + h];
    Wb[e] = s;
}

// ---------------------------------------------------------------------------
__global__ __launch_bounds__(256)
void lowrank_kernel(const float* __restrict__ Aq, const float* __restrict__ Bq,
                    const float* __restrict__ Ak, const float* __restrict__ Bk,
                    const float* __restrict__ rand_gate,
                    float* __restrict__ Mq, float* __restrict__ Mkf)
{
    int t = threadIdx.x;
    for (int e = t; e < 4096; e += 256) {
        int j = e >> 6, d = e & 63;
        float s1 = 0.f, s2 = 0.f;
#pragma unroll
        for (int r = 0; r < 16; ++r) {
            s1 += Aq[j * 16 + r] * Bq[r * 64 + d];
            s2 += Ak[j * 16 + r] * Bk[r * 64 + d];
        }
        Mq[e] = s1;
        Mkf[e] = s2 * 0.5f * tanhf(1.0f + rand_gate[d]);
    }
}

__global__ void init_flag_kernel(int* flagcnt) { *flagcnt = 0; }

// ---------------------------------------------------------------------------
// LSH hash (fp64 from fp32 zm) + near-zero-sim flagging.
// ---------------------------------------------------------------------------
__global__ __launch_bounds__(256)
void hash_flag_kernel(const float* __restrict__ zm, const double* __restrict__ Wb,
                      const float* __restrict__ rot, const int* __restrict__ salts,
                      int* __restrict__ bids, int* __restrict__ flagcnt,
                      int* __restrict__ flagged)
{
    int wave = threadIdx.x >> 6, lane = threadIdx.x & 63;
    int t = blockIdx.x * 4 + wave;
    const float* zrow = zm + (size_t)t * 1024;
    double bacc[8] = {0, 0, 0, 0, 0, 0, 0, 0};
    for (int i = 0; i < 16; ++i) {
        int j = i * 64 + lane;
        double zv = (double)zrow[j];
        const double* wb = Wb + (size_t)j * 8;
#pragma unroll
        for (int h = 0; h < 8; ++h) bacc[h] += zv * wb[h];
    }
#pragma unroll
    for (int h = 0; h < 8; ++h) {
#pragma unroll
        for (int off = 32; off > 0; off >>= 1) bacc[h] += __shfl_xor(bacc[h], off);
    }
    if (lane < 32) {
        int r = lane >> 3, kk = lane & 7;
        double sim = 0.0;
#pragma unroll
        for (int h = 0; h < 8; ++h) sim += bacc[h] * (double)rot[(r * 8 + h) * 8 + kk];
        int m = (sim >= 0.0) ? salts[r * 8 + kk] : 0;
        m ^= __shfl_xor(m, 1);
        m ^= __shfl_xor(m, 2);
        m ^= __shfl_xor(m, 4);
        m ^= __shfl_xor(m, 8);
        m ^= __shfl_xor(m, 16);
        double as = fabs(sim);
#pragma unroll
        for (int off = 16; off > 0; off >>= 1) {
            double o = __shfl_xor(as, off);
            as = fmin(as, o);
        }
        if (lane == 0) {
            bids[t] = m & 31;
            if (as < TAU) {
                int slot = atomicAdd(flagcnt, 1);
                if (slot < MAXFLAG) flagged[slot] = t;
            }
        }
    }
}

// ---------------------------------------------------------------------------
// Exact fp64 recompute of bids for flagged tokens (v2, coalesced). R4-verified.
// ---------------------------------------------------------------------------
__global__ __launch_bounds__(512)
void fixup_kernel(const float* __restrict__ x, const float* __restrict__ ge_inp_w,
                  const float* __restrict__ dw_w, const float* __restrict__ dw_b,
                  const double* __restrict__ Wb, const float* __restrict__ rot,
                  const int* __restrict__ salts, const int* __restrict__ flagcnt,
                  const int* __restrict__ flagged, int* __restrict__ bids)
{
    __shared__ float Lx[3 * 1024];
    __shared__ float Lz[3 * 1024];
    __shared__ float Lg[1024];
    int cnt = *flagcnt; if (cnt > MAXFLAG) cnt = MAXFLAG;
    int s = blockIdx.x;
    if (s >= cnt) return;
    int t = flagged[s];
    int b = t >> 12, n = t & 4095;
    int tid = threadIdx.x;

    for (int idx = tid; idx < 3 * 1024; idx += 512) {
        int r = idx >> 10, d = idx & 1023;
        int row = n + r - 1;
        float v = 0.f;
        if (row >= 0 && row <= 4095) v = x[((size_t)(b * 4096 + row)) * 1024 + d];
        Lx[idx] = v;
    }
    __syncthreads();

    const bool isz = tid < 256;
    const int col = isz ? tid * 4 : 1024 + (tid - 256) * 4;
    const float* wp = ge_inp_w + col;

    double a00 = 0, a01 = 0, a02 = 0, a03 = 0;
    double a10 = 0, a11 = 0, a12 = 0, a13 = 0;
    double a20 = 0, a21 = 0, a22 = 0, a23 = 0;

    for (int m = 0; m < 1024; m += 4) {
        float4 w0 = *(const float4*)(wp + (size_t)(m + 0) * 2048);
        float4 w1 = *(const float4*)(wp + (size_t)(m + 1) * 2048);
        float4 w2 = *(const float4*)(wp + (size_t)(m + 2) * 2048);
        float4 w3 = *(const float4*)(wp + (size_t)(m + 3) * 2048);
        if (isz) {
#pragma unroll
            for (int u = 0; u < 4; ++u) {
                float4 w = (u == 0) ? w0 : (u == 1) ? w1 : (u == 2) ? w2 : w3;
                double x0 = (double)Lx[m + u];
                double x1 = (double)Lx[1024 + m + u];
                double x2 = (double)Lx[2048 + m + u];
                a00 += x0 * (double)w.x; a01 += x0 * (double)w.y;
                a02 += x0 * (double)w.z; a03 += x0 * (double)w.w;
                a10 += x1 * (double)w.x; a11 += x1 * (double)w.y;
                a12 += x1 * (double)w.z; a13 += x1 * (double)w.w;
                a20 += x2 * (double)w.x; a21 += x2 * (double)w.y;
                a22 += x2 * (double)w.z; a23 += x2 * (double)w.w;
            }
        } else {
#pragma unroll
            for (int u = 0; u < 4; ++u) {
                float4 w = (u == 0) ? w0 : (u == 1) ? w1 : (u == 2) ? w2 : w3;
                double xg = (double)Lx[1024 + m + u];
                a00 += xg * (double)w.x; a01 += xg * (double)w.y;
                a02 += xg * (double)w.z; a03 += xg * (double)w.w;
            }
        }
    }

    if (isz) {
        int c = tid * 4;
        Lz[c + 0] = (float)a00; Lz[c + 1] = (float)a01;
        Lz[c + 2] = (float)a02; Lz[c + 3] = (float)a03;
        Lz[1024 + c + 0] = (float)a10; Lz[1024 + c + 1] = (float)a11;
        Lz[1024 + c + 2] = (float)a12; Lz[1024 + c + 3] = (float)a13;
        Lz[2048 + c + 0] = (float)a20; Lz[2048 + c + 1] = (float)a21;
        Lz[2048 + c + 2] = (float)a22; Lz[2048 + c + 3] = (float)a23;
    } else {
        int c = (tid - 256) * 4;
        Lg[c + 0] = (float)a00; Lg[c + 1] = (float)a01;
        Lg[c + 2] = (float)a02; Lg[c + 3] = (float)a03;
    }
    __syncthreads();

    for (int d = tid; d < 1024; d += 512) {
        double z0 = (double)Lz[d];
        double z1 = (double)Lz[1024 + d];
        double z2 = (double)Lz[2048 + d];
        double zc = z0 * (double)dw_w[d * 3 + 0] + z1 * (double)dw_w[d * 3 + 1]
                  + z2 * (double)dw_w[d * 3 + 2] + (double)dw_b[d];
        double g  = (double)Lg[d];
        double sc = zc / (1.0 + exp(-zc));
        double sg = g  / (1.0 + exp(-g));
        Lx[d] = (float)(sc * sg);
    }
    __syncthreads();

    if (tid < 64) {
        int lane = tid;
        double bacc[8] = {0, 0, 0, 0, 0, 0, 0, 0};
        for (int i = 0; i < 16; ++i) {
            int j = i * 64 + lane;
            double zv = (double)Lx[j];
            const double* wb = Wb + (size_t)j * 8;
#pragma unroll
            for (int h = 0; h < 8; ++h) bacc[h] += zv * wb[h];
        }
#pragma unroll
        for (int h = 0; h < 8; ++h) {
#pragma unroll
            for (int off = 32; off > 0; off >>= 1) bacc[h] += __shfl_xor(bacc[h], off);
        }
        if (lane < 32) {
            int r = lane >> 3, kk = lane & 7;
            double sim = 0.0;
#pragma unroll
            for (int h = 0; h < 8; ++h) sim += bacc[h] * (double)rot[(r * 8 + h) * 8 + kk];
            int m = (sim >= 0.0) ? salts[r * 8 + kk] : 0;
            m ^= __shfl_xor(m, 1);
            m ^= __shfl_xor(m, 2);
            m ^= __shfl_xor(m, 4);
            m ^= __shfl_xor(m, 8);
            m ^= __shfl_xor(m, 16);
            if (lane == 0) bids[t] = m & 31;
        }
    }
}

// ---------------------------------------------------------------------------
// Stable counting sort by bucket id. One block per batch.
// ---------------------------------------------------------------------------
__global__ __launch_bounds__(256)
void sort_kernel(const int* __restrict__ bids, int* __restrict__ order)
{
    __shared__ int counts[256 * 33];
    __shared__ int totals[32];
    __shared__ int bbase[32];
    int b = blockIdx.x, t = threadIdx.x;
    const int* bid = bids + b * 4096;
    int* ord = order + b * 4096;
    int* mycnt = counts + t * 33;
#pragma unroll
    for (int i = 0; i < 33; ++i) mycnt[i] = 0;
    int base_i = t * 16;
    int local[16];
#pragma unroll
    for (int i = 0; i < 16; ++i) {
        local[i] = bid[base_i + i];
        mycnt[local[i]]++;
    }
    __syncthreads();
    if (t < 32) {
        int run = 0;
        for (int c = 0; c < 256; ++c) {
            int v = counts[c * 33 + t];
            counts[c * 33 + t] = run;
            run += v;
        }
        totals[t] = run;
    }
    __syncthreads();
    if (t == 0) {
        int s = 0;
        for (int beta = 0; beta < 32; ++beta) { bbase[beta] = s; s += totals[beta]; }
    }
    __syncthreads();
#pragma unroll
    for (int i = 0; i < 16; ++i) {
        int bb = local[i];
        int pos = bbase[bb] + mycnt[bb];
        mycnt[bb]++;
        ord[pos] = base_i + i;
    }
}

// ---------------------------------------------------------------------------
// In-place per-64-row transform: X[r, :] = X[r, :] @ M  (64x64)
// ---------------------------------------------------------------------------
__global__ __launch_bounds__(256)
void rowmat64_kernel(float* __restrict__ X, const float* __restrict__ M)
{
    __shared__ float Xs[64][65];
    __shared__ __align__(16) float Ms[4096];
    int t = threadIdx.x;
    size_t row0 = (size_t)blockIdx.x * 64;
    {
        int r = t >> 2, cg = (t & 3) * 16;
        const float* xp = X + (row0 + r) * 64 + cg;
#pragma unroll
        for (int q = 0; q < 4; ++q) {
            float4 v = *(const float4*)(xp + q * 4);
            Xs[r][cg + q * 4 + 0] = v.x;
            Xs[r][cg + q * 4 + 1] = v.y;
            Xs[r][cg + q * 4 + 2] = v.z;
            Xs[r][cg + q * 4 + 3] = v.w;
        }
        const float* mp = M + t * 16;
#pragma unroll
        for (int q = 0; q < 4; ++q)
            *(float4*)(&Ms[t * 16 + q * 4]) = *(const float4*)(mp + q * 4);
    }
    __syncthreads();
    int c = t & 63, rg = (t >> 6) * 16;
    for (int rr = 0; rr < 16; ++rr) {
        int r = rg + rr;
        float acc = 0.f;
#pragma unroll
        for (int j = 0; j < 64; ++j) acc += Xs[r][j] * Ms[j * 64 + c];
        X[(row0 + r) * 64 + c] = acc;
    }
}

// ---------------------------------------------------------------------------
__global__ __launch_bounds__(256)
void pairmix_kernel(const float* __restrict__ kt0, float* __restrict__ ktm)
{
    int idx = blockIdx.x * 256 + threadIdx.x;
    int cfull = idx & 255;
    int t = idx >> 8;
    int p = t & 4095, b = t >> 12;
    int i = (p < 2048) ? p : (p - 2048);
    float sgn = (p < 2048) ? 1.f : -1.f;
    size_t r0 = ((size_t)(b * 4096 + 2 * i)) * 256 + cfull;
    ktm[idx] = kt0[r0] + sgn * kt0[r0 + 256];
}

// ---------------------------------------------------------------------------
__global__ __launch_bounds__(256)
void cast_bf16_kernel(const float4* __restrict__ in, ushort4* __restrict__ out)
{
    int i = blockIdx.x * 256 + threadIdx.x;
    float4 v = in[i];
    ushort4 o;
    o.x = f2bf(v.x); o.y = f2bf(v.y); o.z = f2bf(v.z); o.w = f2bf(v.w);
    out[i] = o;
}

// ---------------------------------------------------------------------------
__global__ __launch_bounds__(256)
void transpose_cast_kernel(const float* __restrict__ B, __hip_bfloat16* __restrict__ Bt,
                           int K, int N)
{
    __shared__ float tile[32][33];
    int bx = blockIdx.x, by = blockIdx.y;
    int t = threadIdx.x;
    int tr = t >> 5, tc = t & 31;
#pragma unroll
    for (int p = 0; p < 4; ++p)
        tile[tr + p * 8][tc] = B[(size_t)(by * 32 + tr + p * 8) * N + bx * 32 + tc];
    __syncthreads();
#pragma unroll
    for (int p = 0; p < 4; ++p)
        Bt[(size_t)(bx * 32 + tr + p * 8) * K + by * 32 + tc] =
            __float2bfloat16(tile[tc][tr + p * 8]);
}

// ---------------------------------------------------------------------------
// Bucketed attention v2: packed uint4 epilogue stores (fixes 16x write
// amplification), LDS pad 64->68 (breaks 64-way staging bank conflict),
// h-fastest grid (chunk-sharing blocks adjacent for L2 gather locality).
// ---------------------------------------------------------------------------
__global__ __launch_bounds__(256)
void attn_kernel(const float* __restrict__ qt, const float* __restrict__ ktm,
                 const float* __restrict__ v0, const int* __restrict__ order,
                 __hip_bfloat16* __restrict__ o_tok)
{
    __shared__ __align__(16) float Ks[128][68];
    __shared__ __align__(16) float Vs[128][68];
    const int h = blockIdx.x, c = blockIdx.y, b = blockIdx.z;
    const int t = threadIdx.x;
    const int r = t >> 1, hf = t & 1;
    const int kv = h >> 2;
    const int* ord = order + b * 4096 + c * 128;
    const int tokr = ord[r];
    const size_t rowr = (size_t)b * 4096 + tokr;
    {
        const float* kp = ktm + rowr * 256 + kv * 64 + hf * 32;
        const float* vp = v0 + rowr * 256 + kv * 64 + hf * 32;
#pragma unroll
        for (int q = 0; q < 8; ++q) {
            *(float4*)(&Ks[r][hf * 32 + q * 4]) = *(const float4*)(kp + q * 4);
            *(float4*)(&Vs[r][hf * 32 + q * 4]) = *(const float4*)(vp + q * 4);
        }
    }
    float4 qv[16];
    {
        const float* qp = qt + rowr * 1024 + h * 64;
#pragma unroll
        for (int q = 0; q < 16; ++q) qv[q] = *(const float4*)(qp + q * 4);
    }
    __syncthreads();

    float sc[64];
    float mx = -3.0e38f;
    for (int cc = 0; cc < 64; ++cc) {
        const int col = hf * 64 + cc;
        float sx = 0.f, sy = 0.f, sz = 0.f, sw = 0.f;
#pragma unroll
        for (int q = 0; q < 16; ++q) {
            const float4 k4 = *(const float4*)(&Ks[col][q * 4]);
            sx += qv[q].x * k4.x;
            sy += qv[q].y * k4.y;
            sz += qv[q].z * k4.z;
            sw += qv[q].w * k4.w;
        }
        const float s = (sx + sy + sz + sw) * 0.125f;
        sc[cc] = s;
        mx = fmaxf(mx, s);
    }
    mx = fmaxf(mx, __shfl_xor(mx, 1));
    float lsum = 0.f;
    for (int cc = 0; cc < 64; ++cc) {
        const float e = expf(sc[cc] - mx);
        sc[cc] = e;
        lsum += e;
    }
    lsum += __shfl_xor(lsum, 1);
    const float inv = 1.f / lsum;

    float acc[64];
#pragma unroll
    for (int d = 0; d < 64; ++d) acc[d] = 0.f;
    for (int j = 0; j < 64; ++j) {
        const float p = sc[j];
        const int row = hf * 64 + j;
#pragma unroll
        for (int d4 = 0; d4 < 16; ++d4) {
            const float4 v4 = *(const float4*)(&Vs[row][d4 * 4]);
            acc[d4 * 4 + 0] += p * v4.x;
            acc[d4 * 4 + 1] += p * v4.y;
            acc[d4 * 4 + 2] += p * v4.z;
            acc[d4 * 4 + 3] += p * v4.w;
        }
    }
#pragma unroll
    for (int d = 0; d < 64; ++d) acc[d] += __shfl_xor(acc[d], 1);

    // Packed epilogue: 32 bf16 -> 4 x uint4 (16B) stores.
    uint4* op4 = (uint4*)(o_tok + rowr * 1024 + h * 64 + hf * 32);
#pragma unroll
    for (int g = 0; g < 4; ++g) {
        const int base = hf * 32 + g * 8;
        uint4 w;
        w.x = (uint)f2bf(acc[base + 0] * inv) | ((uint)f2bf(acc[base + 1] * inv) << 16);
        w.y = (uint)f2bf(acc[base + 2] * inv) | ((uint)f2bf(acc[base + 3] * inv) << 16);
        w.z = (uint)f2bf(acc[base + 4] * inv) | ((uint)f2bf(acc[base + 5] * inv) << 16);
        w.w = (uint)f2bf(acc[base + 6] * inv) | ((uint)f2bf(acc[base + 7] * inv) << 16);
        op4[g] = w;
    }
}

// ---------------------------------------------------------------------------
extern "C" void kernel_launch(void* const* d_in, const int* in_sizes, int n_in,
                              void* d_out, int out_size, void* d_ws, size_t ws_size,
                              hipStream_t stream)
{
    const float* x         = (const float*)d_in[0];
    const float* ge_inp_w  = (const float*)d_in[1];
    const float* dw_w      = (const float*)d_in[2];
    const float* dw_b      = (const float*)d_in[3];
    const float* ge_out_w  = (const float*)d_in[4];
    const float* q_w       = (const float*)d_in[5];
    const float* k_w       = (const float*)d_in[6];
    const float* v_w       = (const float*)d_in[7];
    const float* Aq        = (const float*)d_in[8];
    const float* Bq        = (const float*)d_in[9];
    const float* Ak        = (const float*)d_in[10];
    const float* Bk        = (const float*)d_in[11];
    const float* rand_gate = (const float*)d_in[12];
    const float* base_w    = (const float*)d_in[13];
    const float* rot       = (const float*)d_in[14];
    const float* o_w       = (const float*)d_in[16];
    const int*   salts     = (const int*)d_in[17];

    char* ws = (char*)d_ws;
    float*          zg       = (float*)(ws + 0);
    __hip_bfloat16* qgkg_bf  = (__hip_bfloat16*)(ws + 0);
    __hip_bfloat16* xo_bf    = (__hip_bfloat16*)(ws + 33554432);
    __hip_bfloat16* Bt_geout = (__hip_bfloat16*)(ws + 50331648);
    __hip_bfloat16* Bt_q     = (__hip_bfloat16*)(ws + 54525952);
    __hip_bfloat16* Bt_k     = (__hip_bfloat16*)(ws + 56623104);
    __hip_bfloat16* Bt_v     = (__hip_bfloat16*)(ws + 57147392);
    __hip_bfloat16* Bt_o     = (__hip_bfloat16*)(ws + 57671680);
    ushort*         A0p      = (ushort*)(ws + 67108864);
    ushort*         A1p      = (ushort*)(ws + 83886080);
    float*          zm       = (float*)(ws + 67108864);
    float*          q0       = (float*)(ws + 67108864);
    ushort*         B0tp     = (ushort*)(ws + 100663296);
    ushort*         B1tp     = (ushort*)(ws + 104857600);
    __hip_bfloat16* zm_bf    = (__hip_bfloat16*)(ws + 100663296);
    float*          k0       = (float*)(ws + 100663296);
    float*          v0       = (float*)(ws + 109051904);
    float*          ktm      = (float*)(ws + 117440512);
    float*          Mq       = (float*)(ws + 125829120);
    float*          Mkf      = (float*)(ws + 125845504);
    double*         Wb       = (double*)(ws + 125861888);
    int*            bids     = (int*)(ws + 125927424);
    int*            order    = (int*)(ws + 125960192);
    int*            flagcnt  = (int*)(ws + 125992960);
    int*            flagged  = (int*)(ws + 125993216);
    float*          outp     = (float*)d_out;

    // Precomputes
    init_flag_kernel<<<1, 1, 0, stream>>>(flagcnt);
    lowrank_kernel<<<1, 256, 0, stream>>>(Aq, Bq, Ak, Bk, rand_gate, Mq, Mkf);
    wb_kernel<<<32, 256, 0, stream>>>(ge_out_w, base_w, Wb);
    split_a_kernel<<<8192, 256, 0, stream>>>((const float4*)x, (ushort4*)A0p, (ushort4*)A1p);
    split_bt2_kernel<<<dim3(64, 32), 256, 0, stream>>>(ge_inp_w, B0tp, B1tp);

    // GEMM1 (2-plane bf16-split MFMA): zg = x @ ge_inp_w  [8192x2048]
    gemm1_mfma2<<<dim3(16, 64), 256, 0, stream>>>(A0p, A1p, B0tp, B1tp, zg);
    // conv + silu*silu -> zm fp32 (over A0/A1) + zm_bf (over B0t/B1t)
    conv_silu_kernel<<<32768, 256, 0, stream>>>(zg, dw_w, dw_b, zm, zm_bf);

    // Casts / weight transposes (zg dead now)
    cast_bf16_kernel<<<8192, 256, 0, stream>>>((const float4*)x, (ushort4*)xo_bf);
    transpose_cast_kernel<<<dim3(64, 32), 256, 0, stream>>>(ge_out_w, Bt_geout, 1024, 2048);
    transpose_cast_kernel<<<dim3(32, 32), 256, 0, stream>>>(q_w, Bt_q, 1024, 1024);
    transpose_cast_kernel<<<dim3(8, 32), 256, 0, stream>>>(k_w, Bt_k, 1024, 256);
    transpose_cast_kernel<<<dim3(8, 32), 256, 0, stream>>>(v_w, Bt_v, 1024, 256);
    transpose_cast_kernel<<<dim3(32, 32), 256, 0, stream>>>(o_w, Bt_o, 1024, 1024);

    // GEMM2 (bf16 MFMA): qgkg_bf = zm_bf @ ge_out_w  [8192x2048]
    gemm_mfma_bt<__hip_bfloat16><<<dim3(16, 64), 256, 0, stream>>>(
        (const ushort*)zm_bf, 1024, (const ushort*)Bt_geout, qgkg_bf, 2048, 1024);

    // hash + flag -> bids; exact fixup for near-zero sims; stable sort
    hash_flag_kernel<<<2048, 256, 0, stream>>>(zm, Wb, rot, salts, bids, flagcnt, flagged);
    fixup_kernel<<<MAXFLAG, 512, 0, stream>>>(x, ge_inp_w, dw_w, dw_b, Wb, rot, salts,
                                              flagcnt, flagged, bids);
    sort_kernel<<<2, 256, 0, stream>>>(bids, order);

    // q0 = qg @ q_w [8192x1024] (overwrites zm; hash done)
    gemm_mfma_bt<float><<<dim3(8, 64), 256, 0, stream>>>(
        (const ushort*)qgkg_bf, 2048, (const ushort*)Bt_q, q0, 1024, 1024);
    rowmat64_kernel<<<2048, 256, 0, stream>>>(q0, Mq);

    // k0 = kg @ k_w [8192x256] (overwrites zm_bf; GEMM2 + fixup done)
    gemm_mfma_bt<float><<<dim3(2, 64), 256, 0, stream>>>(
        (const ushort*)(qgkg_bf + 1024), 2048, (const ushort*)Bt_k, k0, 256, 1024);
    rowmat64_kernel<<<512, 256, 0, stream>>>(k0, Mkf);
    pairmix_kernel<<<8192, 256, 0, stream>>>(k0, ktm);

    // v0 = x @ v_w [8192x256]
    gemm_mfma_bt<float><<<dim3(2, 64), 256, 0, stream>>>(
        (const ushort*)xo_bf, 1024, (const ushort*)Bt_v, v0, 256, 1024);

    // bucketed attention -> o_bf (overwrites x_bf); h-fastest grid
    attn_kernel<<<dim3(16, 32, 2), 256, 0, stream>>>(q0, ktm, v0, order, xo_bf);

    // final: out = o @ o_w [8192x1024]
    gemm_mfma_bt<float><<<dim3(8, 64), 256, 0, stream>>>(
        (const ushort*)xo_bf, 1024, (const ushort*)Bt_o, outp, 1024, 1024);
}

// Round 6
// 926.829 us; speedup vs baseline: 1.5628x; 1.0103x over previous
//
#include <hip/hip_runtime.h>
#include <hip/hip_bf16.h>
#include <math.h>

typedef __attribute__((ext_vector_type(8))) short short8;
typedef __attribute__((ext_vector_type(4))) float f32x4;

#define MAXFLAG 512
#define TAU 8e-6

__device__ inline ushort f2bf(float f) {
    __hip_bfloat16 h = __float2bfloat16(f);
    return *reinterpret_cast<ushort*>(&h);
}

// Split fp32 v into 2 bf16 terms (v = b0 + b1 + O(2^-18 v)).
__device__ inline void split2_one(float v, ushort& h0, ushort& h1) {
    __hip_bfloat16 b0 = __float2bfloat16(v);
    float f0 = __bfloat162float(b0);
    __hip_bfloat16 b1 = __float2bfloat16(v - f0);
    h0 = *reinterpret_cast<ushort*>(&b0);
    h1 = *reinterpret_cast<ushort*>(&b1);
}

// ---------------------------------------------------------------------------
// x [8192x1024] fp32 -> two bf16 planes (row-major, same layout)
// ---------------------------------------------------------------------------
__global__ __launch_bounds__(256)
void split_a_kernel(const float4* __restrict__ in, ushort4* __restrict__ o0,
                    ushort4* __restrict__ o1)
{
    int i = blockIdx.x * 256 + threadIdx.x;
    float4 v = in[i];
    ushort4 a, b;
    split2_one(v.x, a.x, b.x);
    split2_one(v.y, a.y, b.y);
    split2_one(v.z, a.z, b.z);
    split2_one(v.w, a.w, b.w);
    o0[i] = a;
    o1[i] = b;
}

// ---------------------------------------------------------------------------
// ge_inp_w [1024 k][2048 n] fp32 -> 2 bf16 split planes [2048 n][1024 k]
// ---------------------------------------------------------------------------
__global__ __launch_bounds__(256)
void split_bt2_kernel(const float* __restrict__ B, ushort* __restrict__ t0,
                      ushort* __restrict__ t1)
{
    __shared__ float tile[32][33];
    int bx = blockIdx.x, by = blockIdx.y;
    int t = threadIdx.x;
    int tr = t >> 5, tc = t & 31;
#pragma unroll
    for (int p = 0; p < 4; ++p)
        tile[tr + p * 8][tc] = B[(size_t)(by * 32 + tr + p * 8) * 2048 + bx * 32 + tc];
    __syncthreads();
#pragma unroll
    for (int p = 0; p < 4; ++p) {
        float v = tile[tc][tr + p * 8];
        ushort h0, h1;
        split2_one(v, h0, h1);
        size_t off = (size_t)(bx * 32 + tr + p * 8) * 1024 + by * 32 + tc;
        t0[off] = h0; t1[off] = h1;
    }
}

// ---------------------------------------------------------------------------
// GEMM1: C[8192,2048] = A @ B with 2-plane bf16 split on both operands.
// ---------------------------------------------------------------------------
__global__ __launch_bounds__(256)
void gemm1_mfma2(const ushort* __restrict__ A0, const ushort* __restrict__ A1,
                 const ushort* __restrict__ B0t, const ushort* __restrict__ B1t,
                 float* __restrict__ C)
{
    __shared__ __attribute__((aligned(16))) ushort As0[128 * 32];
    __shared__ __attribute__((aligned(16))) ushort As1[128 * 32];
    __shared__ __attribute__((aligned(16))) ushort Bs0[128 * 32];
    __shared__ __attribute__((aligned(16))) ushort Bs1[128 * 32];
    const int tid = threadIdx.x;
    const int wave = tid >> 6, lane = tid & 63;
    const int m0 = blockIdx.y * 128, n0 = blockIdx.x * 128;
    const int wm = (wave >> 1) * 64, wn = (wave & 1) * 64;

    f32x4 acc[4][4] = {};

    const int r0 = (wave * 2 + 0) * 16 + (lane >> 2);
    const int r1 = (wave * 2 + 1) * 16 + (lane >> 2);
    const int kc = (lane & 3) * 8;

    for (int k0 = 0; k0 < 1024; k0 += 32) {
        size_t ga0 = (size_t)(m0 + r0) * 1024 + k0 + kc;
        size_t ga1 = (size_t)(m0 + r1) * 1024 + k0 + kc;
        size_t gb0 = (size_t)(n0 + r0) * 1024 + k0 + kc;
        size_t gb1 = (size_t)(n0 + r1) * 1024 + k0 + kc;
        const int l0 = (wave * 2 + 0) * 512, l1 = (wave * 2 + 1) * 512;
        __builtin_amdgcn_global_load_lds(
            (const __attribute__((address_space(1))) unsigned int*)(A0 + ga0),
            (__attribute__((address_space(3))) unsigned int*)(As0 + l0), 16, 0, 0);
        __builtin_amdgcn_global_load_lds(
            (const __attribute__((address_space(1))) unsigned int*)(A0 + ga1),
            (__attribute__((address_space(3))) unsigned int*)(As0 + l1), 16, 0, 0);
        __builtin_amdgcn_global_load_lds(
            (const __attribute__((address_space(1))) unsigned int*)(A1 + ga0),
            (__attribute__((address_space(3))) unsigned int*)(As1 + l0), 16, 0, 0);
        __builtin_amdgcn_global_load_lds(
            (const __attribute__((address_space(1))) unsigned int*)(A1 + ga1),
            (__attribute__((address_space(3))) unsigned int*)(As1 + l1), 16, 0, 0);
        __builtin_amdgcn_global_load_lds(
            (const __attribute__((address_space(1))) unsigned int*)(B0t + gb0),
            (__attribute__((address_space(3))) unsigned int*)(Bs0 + l0), 16, 0, 0);
        __builtin_amdgcn_global_load_lds(
            (const __attribute__((address_space(1))) unsigned int*)(B0t + gb1),
            (__attribute__((address_space(3))) unsigned int*)(Bs0 + l1), 16, 0, 0);
        __builtin_amdgcn_global_load_lds(
            (const __attribute__((address_space(1))) unsigned int*)(B1t + gb0),
            (__attribute__((address_space(3))) unsigned int*)(Bs1 + l0), 16, 0, 0);
        __builtin_amdgcn_global_load_lds(
            (const __attribute__((address_space(1))) unsigned int*)(B1t + gb1),
            (__attribute__((address_space(3))) unsigned int*)(Bs1 + l1), 16, 0, 0);
        __syncthreads();

        short8 af0[4], af1[4], bf0[4], bf1[4];
#pragma unroll
        for (int t = 0; t < 4; ++t) {
            int aoff = (wm + t * 16 + (lane & 15)) * 32 + (lane >> 4) * 8;
            int boff = (wn + t * 16 + (lane & 15)) * 32 + (lane >> 4) * 8;
            af0[t] = *(const short8*)(As0 + aoff);
            af1[t] = *(const short8*)(As1 + aoff);
            bf0[t] = *(const short8*)(Bs0 + boff);
            bf1[t] = *(const short8*)(Bs1 + boff);
        }
#pragma unroll
        for (int i = 0; i < 4; ++i)
#pragma unroll
            for (int j = 0; j < 4; ++j) {
                acc[i][j] = __builtin_amdgcn_mfma_f32_16x16x32_bf16(af0[i], bf0[j], acc[i][j], 0, 0, 0);
                acc[i][j] = __builtin_amdgcn_mfma_f32_16x16x32_bf16(af0[i], bf1[j], acc[i][j], 0, 0, 0);
                acc[i][j] = __builtin_amdgcn_mfma_f32_16x16x32_bf16(af1[i], bf0[j], acc[i][j], 0, 0, 0);
            }
        __syncthreads();
    }
#pragma unroll
    for (int i = 0; i < 4; ++i) {
        const int rowb = m0 + wm + i * 16 + (lane >> 4) * 4;
#pragma unroll
        for (int j = 0; j < 4; ++j) {
            const int col = n0 + wn + j * 16 + (lane & 15);
#pragma unroll
            for (int r = 0; r < 4; ++r)
                C[(size_t)(rowb + r) * 2048 + col] = acc[i][j][r];
        }
    }
}

// ---------------------------------------------------------------------------
// bf16 MFMA GEMM (m97 structure) — verified R2-R5.
// ---------------------------------------------------------------------------
__device__ inline void storeC(float v, float* p) { *p = v; }
__device__ inline void storeC(float v, __hip_bfloat16* p) { *p = __float2bfloat16(v); }

template <typename OutT>
__global__ __launch_bounds__(256)
void gemm_mfma_bt(const ushort* __restrict__ A, int lda,
                  const ushort* __restrict__ Bt,
                  OutT* __restrict__ C, int ldc, int K)
{
    __shared__ __attribute__((aligned(16))) ushort As[128 * 32];
    __shared__ __attribute__((aligned(16))) ushort Bs[128 * 32];
    const int tid = threadIdx.x;
    const int wave = tid >> 6, lane = tid & 63;
    const int m0 = blockIdx.y * 128, n0 = blockIdx.x * 128;
    const int wm = (wave >> 1) * 64, wn = (wave & 1) * 64;

    f32x4 acc[4][4] = {};

    const int r0 = (wave * 2 + 0) * 16 + (lane >> 2);
    const int r1 = (wave * 2 + 1) * 16 + (lane >> 2);
    const int kc = (lane & 3) * 8;

    for (int k0 = 0; k0 < K; k0 += 32) {
        const ushort* ga0 = A + (size_t)(m0 + r0) * lda + k0 + kc;
        const ushort* ga1 = A + (size_t)(m0 + r1) * lda + k0 + kc;
        const ushort* gb0 = Bt + (size_t)(n0 + r0) * K + k0 + kc;
        const ushort* gb1 = Bt + (size_t)(n0 + r1) * K + k0 + kc;
        __builtin_amdgcn_global_load_lds(
            (const __attribute__((address_space(1))) unsigned int*)ga0,
            (__attribute__((address_space(3))) unsigned int*)(As + (wave * 2 + 0) * 512),
            16, 0, 0);
        __builtin_amdgcn_global_load_lds(
            (const __attribute__((address_space(1))) unsigned int*)ga1,
            (__attribute__((address_space(3))) unsigned int*)(As + (wave * 2 + 1) * 512),
            16, 0, 0);
        __builtin_amdgcn_global_load_lds(
            (const __attribute__((address_space(1))) unsigned int*)gb0,
            (__attribute__((address_space(3))) unsigned int*)(Bs + (wave * 2 + 0) * 512),
            16, 0, 0);
        __builtin_amdgcn_global_load_lds(
            (const __attribute__((address_space(1))) unsigned int*)gb1,
            (__attribute__((address_space(3))) unsigned int*)(Bs + (wave * 2 + 1) * 512),
            16, 0, 0);
        __syncthreads();

        short8 af[4], bfr[4];
#pragma unroll
        for (int t = 0; t < 4; ++t) {
            af[t]  = *(const short8*)(As + (wm + t * 16 + (lane & 15)) * 32 + (lane >> 4) * 8);
            bfr[t] = *(const short8*)(Bs + (wn + t * 16 + (lane & 15)) * 32 + (lane >> 4) * 8);
        }
#pragma unroll
        for (int i = 0; i < 4; ++i)
#pragma unroll
            for (int j = 0; j < 4; ++j)
                acc[i][j] = __builtin_amdgcn_mfma_f32_16x16x32_bf16(af[i], bfr[j], acc[i][j], 0, 0, 0);
        __syncthreads();
    }

#pragma unroll
    for (int i = 0; i < 4; ++i) {
        const int rowb = m0 + wm + i * 16 + (lane >> 4) * 4;
#pragma unroll
        for (int j = 0; j < 4; ++j) {
            const int col = n0 + wn + j * 16 + (lane & 15);
#pragma unroll
            for (int r = 0; r < 4; ++r)
                storeC(acc[i][j][r], C + (size_t)(rowb + r) * ldc + col);
        }
    }
}

// ---------------------------------------------------------------------------
// conv width-3 + silu*silu, fp32 (fixup covers sign-critical tokens).
// ---------------------------------------------------------------------------
__global__ __launch_bounds__(256)
void conv_silu_kernel(const float* __restrict__ zg, const float* __restrict__ dw_w,
                      const float* __restrict__ dw_b, float* __restrict__ zm,
                      __hip_bfloat16* __restrict__ zmb)
{
    int idx = blockIdx.x * 256 + threadIdx.x;
    int d = idx & 1023;
    int t = idx >> 10;
    int n = t & 4095;
    const float* zrow = zg + (size_t)t * 2048;
    float z0 = (n > 0)    ? zg[(size_t)(t - 1) * 2048 + d] : 0.f;
    float z1 = zrow[d];
    float z2 = (n < 4095) ? zg[(size_t)(t + 1) * 2048 + d] : 0.f;
    float zc = z0 * dw_w[d * 3 + 0] + z1 * dw_w[d * 3 + 1] + z2 * dw_w[d * 3 + 2] + dw_b[d];
    float g  = zrow[1024 + d];
    float sc = zc / (1.f + expf(-zc));
    float sg = g  / (1.f + expf(-g));
    float r = sc * sg;
    zm[idx] = r;
    zmb[idx] = __float2bfloat16(r);
}

// ---------------------------------------------------------------------------
// Wb[j][h] = sum_m ge_out_w[j, m] * base_w[m, h]  (fp64; 1024x8)
// ---------------------------------------------------------------------------
__global__ __launch_bounds__(256)
void wb_kernel(const float* __restrict__ ge_out_w, const float* __restrict__ base_w,
               double* __restrict__ Wb)
{
    int e = blockIdx.x * 256 + threadIdx.x;
    int j = e >> 3, h = e & 7;
    const float* wr = ge_out_w + (size_t)j * 2048;
    double s = 0.0;
    for (int m = 0; m < 1024; ++m) s += (double)wr[m] * (double)base_w[m * 8 + h];
    Wb[e] = s;
}

// ---------------------------------------------------------------------------
__global__ __launch_bounds__(256)
void lowrank_kernel(const float* __restrict__ Aq, const float* __restrict__ Bq,
                    const float* __restrict__ Ak, const float* __restrict__ Bk,
                    const float* __restrict__ rand_gate,
                    float* __restrict__ Mq, float* __restrict__ Mkf)
{
    int t = threadIdx.x;
    for (int e = t; e < 4096; e += 256) {
        int j = e >> 6, d = e & 63;
        float s1 = 0.f, s2 = 0.f;
#pragma unroll
        for (int r = 0; r < 16; ++r) {
            s1 += Aq[j * 16 + r] * Bq[r * 64 + d];
            s2 += Ak[j * 16 + r] * Bk[r * 64 + d];
        }
        Mq[e] = s1;
        Mkf[e] = s2 * 0.5f * tanhf(1.0f + rand_gate[d]);
    }
}

__global__ void init_flag_kernel(int* flagcnt) { *flagcnt = 0; }

// ---------------------------------------------------------------------------
// LSH hash (fp64 from fp32 zm) + near-zero-sim flagging.
// ---------------------------------------------------------------------------
__global__ __launch_bounds__(256)
void hash_flag_kernel(const float* __restrict__ zm, const double* __restrict__ Wb,
                      const float* __restrict__ rot, const int* __restrict__ salts,
                      int* __restrict__ bids, int* __restrict__ flagcnt,
                      int* __restrict__ flagged)
{
    int wave = threadIdx.x >> 6, lane = threadIdx.x & 63;
    int t = blockIdx.x * 4 + wave;
    const float* zrow = zm + (size_t)t * 1024;
    double bacc[8] = {0, 0, 0, 0, 0, 0, 0, 0};
    for (int i = 0; i < 16; ++i) {
        int j = i * 64 + lane;
        double zv = (double)zrow[j];
        const double* wb = Wb + (size_t)j * 8;
#pragma unroll
        for (int h = 0; h < 8; ++h) bacc[h] += zv * wb[h];
    }
#pragma unroll
    for (int h = 0; h < 8; ++h) {
#pragma unroll
        for (int off = 32; off > 0; off >>= 1) bacc[h] += __shfl_xor(bacc[h], off);
    }
    if (lane < 32) {
        int r = lane >> 3, kk = lane & 7;
        double sim = 0.0;
#pragma unroll
        for (int h = 0; h < 8; ++h) sim += bacc[h] * (double)rot[(r * 8 + h) * 8 + kk];
        int m = (sim >= 0.0) ? salts[r * 8 + kk] : 0;
        m ^= __shfl_xor(m, 1);
        m ^= __shfl_xor(m, 2);
        m ^= __shfl_xor(m, 4);
        m ^= __shfl_xor(m, 8);
        m ^= __shfl_xor(m, 16);
        double as = fabs(sim);
#pragma unroll
        for (int off = 16; off > 0; off >>= 1) {
            double o = __shfl_xor(as, off);
            as = fmin(as, o);
        }
        if (lane == 0) {
            bids[t] = m & 31;
            if (as < TAU) {
                int slot = atomicAdd(flagcnt, 1);
                if (slot < MAXFLAG) flagged[slot] = t;
            }
        }
    }
}

// ---------------------------------------------------------------------------
// Exact fp64 recompute of bids for flagged tokens (v2, coalesced). R4-verified.
// ---------------------------------------------------------------------------
__global__ __launch_bounds__(512)
void fixup_kernel(const float* __restrict__ x, const float* __restrict__ ge_inp_w,
                  const float* __restrict__ dw_w, const float* __restrict__ dw_b,
                  const double* __restrict__ Wb, const float* __restrict__ rot,
                  const int* __restrict__ salts, const int* __restrict__ flagcnt,
                  const int* __restrict__ flagged, int* __restrict__ bids)
{
    __shared__ float Lx[3 * 1024];
    __shared__ float Lz[3 * 1024];
    __shared__ float Lg[1024];
    int cnt = *flagcnt; if (cnt > MAXFLAG) cnt = MAXFLAG;
    int s = blockIdx.x;
    if (s >= cnt) return;
    int t = flagged[s];
    int b = t >> 12, n = t & 4095;
    int tid = threadIdx.x;

    for (int idx = tid; idx < 3 * 1024; idx += 512) {
        int r = idx >> 10, d = idx & 1023;
        int row = n + r - 1;
        float v = 0.f;
        if (row >= 0 && row <= 4095) v = x[((size_t)(b * 4096 + row)) * 1024 + d];
        Lx[idx] = v;
    }
    __syncthreads();

    const bool isz = tid < 256;
    const int col = isz ? tid * 4 : 1024 + (tid - 256) * 4;
    const float* wp = ge_inp_w + col;

    double a00 = 0, a01 = 0, a02 = 0, a03 = 0;
    double a10 = 0, a11 = 0, a12 = 0, a13 = 0;
    double a20 = 0, a21 = 0, a22 = 0, a23 = 0;

    for (int m = 0; m < 1024; m += 4) {
        float4 w0 = *(const float4*)(wp + (size_t)(m + 0) * 2048);
        float4 w1 = *(const float4*)(wp + (size_t)(m + 1) * 2048);
        float4 w2 = *(const float4*)(wp + (size_t)(m + 2) * 2048);
        float4 w3 = *(const float4*)(wp + (size_t)(m + 3) * 2048);
        if (isz) {
#pragma unroll
            for (int u = 0; u < 4; ++u) {
                float4 w = (u == 0) ? w0 : (u == 1) ? w1 : (u == 2) ? w2 : w3;
                double x0 = (double)Lx[m + u];
                double x1 = (double)Lx[1024 + m + u];
                double x2 = (double)Lx[2048 + m + u];
                a00 += x0 * (double)w.x; a01 += x0 * (double)w.y;
                a02 += x0 * (double)w.z; a03 += x0 * (double)w.w;
                a10 += x1 * (double)w.x; a11 += x1 * (double)w.y;
                a12 += x1 * (double)w.z; a13 += x1 * (double)w.w;
                a20 += x2 * (double)w.x; a21 += x2 * (double)w.y;
                a22 += x2 * (double)w.z; a23 += x2 * (double)w.w;
            }
        } else {
#pragma unroll
            for (int u = 0; u < 4; ++u) {
                float4 w = (u == 0) ? w0 : (u == 1) ? w1 : (u == 2) ? w2 : w3;
                double xg = (double)Lx[1024 + m + u];
                a00 += xg * (double)w.x; a01 += xg * (double)w.y;
                a02 += xg * (double)w.z; a03 += xg * (double)w.w;
            }
        }
    }

    if (isz) {
        int c = tid * 4;
        Lz[c + 0] = (float)a00; Lz[c + 1] = (float)a01;
        Lz[c + 2] = (float)a02; Lz[c + 3] = (float)a03;
        Lz[1024 + c + 0] = (float)a10; Lz[1024 + c + 1] = (float)a11;
        Lz[1024 + c + 2] = (float)a12; Lz[1024 + c + 3] = (float)a13;
        Lz[2048 + c + 0] = (float)a20; Lz[2048 + c + 1] = (float)a21;
        Lz[2048 + c + 2] = (float)a22; Lz[2048 + c + 3] = (float)a23;
    } else {
        int c = (tid - 256) * 4;
        Lg[c + 0] = (float)a00; Lg[c + 1] = (float)a01;
        Lg[c + 2] = (float)a02; Lg[c + 3] = (float)a03;
    }
    __syncthreads();

    for (int d = tid; d < 1024; d += 512) {
        double z0 = (double)Lz[d];
        double z1 = (double)Lz[1024 + d];
        double z2 = (double)Lz[2048 + d];
        double zc = z0 * (double)dw_w[d * 3 + 0] + z1 * (double)dw_w[d * 3 + 1]
                  + z2 * (double)dw_w[d * 3 + 2] + (double)dw_b[d];
        double g  = (double)Lg[d];
        double sc = zc / (1.0 + exp(-zc));
        double sg = g  / (1.0 + exp(-g));
        Lx[d] = (float)(sc * sg);
    }
    __syncthreads();

    if (tid < 64) {
        int lane = tid;
        double bacc[8] = {0, 0, 0, 0, 0, 0, 0, 0};
        for (int i = 0; i < 16; ++i) {
            int j = i * 64 + lane;
            double zv = (double)Lx[j];
            const double* wb = Wb + (size_t)j * 8;
#pragma unroll
            for (int h = 0; h < 8; ++h) bacc[h] += zv * wb[h];
        }
#pragma unroll
        for (int h = 0; h < 8; ++h) {
#pragma unroll
            for (int off = 32; off > 0; off >>= 1) bacc[h] += __shfl_xor(bacc[h], off);
        }
        if (lane < 32) {
            int r = lane >> 3, kk = lane & 7;
            double sim = 0.0;
#pragma unroll
            for (int h = 0; h < 8; ++h) sim += bacc[h] * (double)rot[(r * 8 + h) * 8 + kk];
            int m = (sim >= 0.0) ? salts[r * 8 + kk] : 0;
            m ^= __shfl_xor(m, 1);
            m ^= __shfl_xor(m, 2);
            m ^= __shfl_xor(m, 4);
            m ^= __shfl_xor(m, 8);
            m ^= __shfl_xor(m, 16);
            if (lane == 0) bids[t] = m & 31;
        }
    }
}

// ---------------------------------------------------------------------------
// Stable counting sort by bucket id. One block per batch.
// ---------------------------------------------------------------------------
__global__ __launch_bounds__(256)
void sort_kernel(const int* __restrict__ bids, int* __restrict__ order)
{
    __shared__ int counts[256 * 33];
    __shared__ int totals[32];
    __shared__ int bbase[32];
    int b = blockIdx.x, t = threadIdx.x;
    const int* bid = bids + b * 4096;
    int* ord = order + b * 4096;
    int* mycnt = counts + t * 33;
#pragma unroll
    for (int i = 0; i < 33; ++i) mycnt[i] = 0;
    int base_i = t * 16;
    int local[16];
#pragma unroll
    for (int i = 0; i < 16; ++i) {
        local[i] = bid[base_i + i];
        mycnt[local[i]]++;
    }
    __syncthreads();
    if (t < 32) {
        int run = 0;
        for (int c = 0; c < 256; ++c) {
            int v = counts[c * 33 + t];
            counts[c * 33 + t] = run;
            run += v;
        }
        totals[t] = run;
    }
    __syncthreads();
    if (t == 0) {
        int s = 0;
        for (int beta = 0; beta < 32; ++beta) { bbase[beta] = s; s += totals[beta]; }
    }
    __syncthreads();
#pragma unroll
    for (int i = 0; i < 16; ++i) {
        int bb = local[i];
        int pos = bbase[bb] + mycnt[bb];
        mycnt[bb]++;
        ord[pos] = base_i + i;
    }
}

// ---------------------------------------------------------------------------
// In-place per-64-row transform: X[r, :] = X[r, :] @ M  (64x64)
// ---------------------------------------------------------------------------
__global__ __launch_bounds__(256)
void rowmat64_kernel(float* __restrict__ X, const float* __restrict__ M)
{
    __shared__ float Xs[64][65];
    __shared__ __align__(16) float Ms[4096];
    int t = threadIdx.x;
    size_t row0 = (size_t)blockIdx.x * 64;
    {
        int r = t >> 2, cg = (t & 3) * 16;
        const float* xp = X + (row0 + r) * 64 + cg;
#pragma unroll
        for (int q = 0; q < 4; ++q) {
            float4 v = *(const float4*)(xp + q * 4);
            Xs[r][cg + q * 4 + 0] = v.x;
            Xs[r][cg + q * 4 + 1] = v.y;
            Xs[r][cg + q * 4 + 2] = v.z;
            Xs[r][cg + q * 4 + 3] = v.w;
        }
        const float* mp = M + t * 16;
#pragma unroll
        for (int q = 0; q < 4; ++q)
            *(float4*)(&Ms[t * 16 + q * 4]) = *(const float4*)(mp + q * 4);
    }
    __syncthreads();
    int c = t & 63, rg = (t >> 6) * 16;
    for (int rr = 0; rr < 16; ++rr) {
        int r = rg + rr;
        float acc = 0.f;
#pragma unroll
        for (int j = 0; j < 64; ++j) acc += Xs[r][j] * Ms[j * 64 + c];
        X[(row0 + r) * 64 + c] = acc;
    }
}

// ---------------------------------------------------------------------------
__global__ __launch_bounds__(256)
void pairmix_kernel(const float* __restrict__ kt0, float* __restrict__ ktm)
{
    int idx = blockIdx.x * 256 + threadIdx.x;
    int cfull = idx & 255;
    int t = idx >> 8;
    int p = t & 4095, b = t >> 12;
    int i = (p < 2048) ? p : (p - 2048);
    float sgn = (p < 2048) ? 1.f : -1.f;
    size_t r0 = ((size_t)(b * 4096 + 2 * i)) * 256 + cfull;
    ktm[idx] = kt0[r0] + sgn * kt0[r0 + 256];
}

// ---------------------------------------------------------------------------
__global__ __launch_bounds__(256)
void cast_bf16_kernel(const float4* __restrict__ in, ushort4* __restrict__ out)
{
    int i = blockIdx.x * 256 + threadIdx.x;
    float4 v = in[i];
    ushort4 o;
    o.x = f2bf(v.x); o.y = f2bf(v.y); o.z = f2bf(v.z); o.w = f2bf(v.w);
    out[i] = o;
}

// ---------------------------------------------------------------------------
__global__ __launch_bounds__(256)
void transpose_cast_kernel(const float* __restrict__ B, __hip_bfloat16* __restrict__ Bt,
                           int K, int N)
{
    __shared__ float tile[32][33];
    int bx = blockIdx.x, by = blockIdx.y;
    int t = threadIdx.x;
    int tr = t >> 5, tc = t & 31;
#pragma unroll
    for (int p = 0; p < 4; ++p)
        tile[tr + p * 8][tc] = B[(size_t)(by * 32 + tr + p * 8) * N + bx * 32 + tc];
    __syncthreads();
#pragma unroll
    for (int p = 0; p < 4; ++p)
        Bt[(size_t)(bx * 32 + tr + p * 8) * K + by * 32 + tc] =
            __float2bfloat16(tile[tc][tr + p * 8]);
}

// ---------------------------------------------------------------------------
// Bucketed attention v3: no dynamically-indexed private arrays (sc[] stays in
// VGPRs via fully-unrolled inner loops; PV chunked over output dims with 8
// accumulators). __launch_bounds__(256,2) allows up to 256 VGPRs (LDS caps
// occupancy at 2 blocks/CU anyway). LDS compute reads are wave-broadcast.
// ---------------------------------------------------------------------------
__global__ __launch_bounds__(256, 2)
void attn_kernel(const float* __restrict__ qt, const float* __restrict__ ktm,
                 const float* __restrict__ v0, const int* __restrict__ order,
                 __hip_bfloat16* __restrict__ o_tok)
{
    __shared__ __align__(16) float Ks[128][68];
    __shared__ __align__(16) float Vs[128][68];
    const int c = blockIdx.x, h = blockIdx.y, b = blockIdx.z;
    const int t = threadIdx.x;
    const int r = t >> 1, hf = t & 1;
    const int kv = h >> 2;
    const int tokr = order[b * 4096 + c * 128 + r];
    const size_t rowr = (size_t)b * 4096 + tokr;
    {
        const float* kp = ktm + rowr * 256 + kv * 64 + hf * 32;
        const float* vp = v0 + rowr * 256 + kv * 64 + hf * 32;
#pragma unroll
        for (int q = 0; q < 8; ++q) {
            *(float4*)(&Ks[r][hf * 32 + q * 4]) = *(const float4*)(kp + q * 4);
            *(float4*)(&Vs[r][hf * 32 + q * 4]) = *(const float4*)(vp + q * 4);
        }
    }
    float4 qv[16];
    {
        const float* qp = qt + rowr * 1024 + h * 64;
#pragma unroll
        for (int q = 0; q < 16; ++q) qv[q] = *(const float4*)(qp + q * 4);
    }
    __syncthreads();

    // Score pass: thread (r,hf) computes cols hf*64..hf*64+63 of row r.
    // Outer loop runtime (16 q-chunks); inner fully unrolled -> sc[] in regs.
    float sc[64];
#pragma unroll
    for (int cc = 0; cc < 64; ++cc) sc[cc] = 0.f;
    const int col0 = hf * 64;
    for (int q4 = 0; q4 < 16; ++q4) {
        const float4 q = qv[q4];
#pragma unroll
        for (int cc = 0; cc < 64; ++cc) {
            const float4 k4 = *(const float4*)(&Ks[col0 + cc][q4 * 4]);
            sc[cc] += q.x * k4.x + q.y * k4.y + q.z * k4.z + q.w * k4.w;
        }
    }

    float mx = -3.0e38f;
#pragma unroll
    for (int cc = 0; cc < 64; ++cc) {
        sc[cc] *= 0.125f;
        mx = fmaxf(mx, sc[cc]);
    }
    mx = fmaxf(mx, __shfl_xor(mx, 1));
    float lsum = 0.f;
#pragma unroll
    for (int cc = 0; cc < 64; ++cc) {
        sc[cc] = expf(sc[cc] - mx);
        lsum += sc[cc];
    }
    lsum += __shfl_xor(lsum, 1);
    const float inv = 1.f / lsum;

    // PV pass: runtime loop over 8 output-dim chunks; inner j fully unrolled.
    // Thread accumulates its own 64 j's; pair shfl-add merges halves.
    for (int d8 = 0; d8 < 8; ++d8) {
        float a0 = 0.f, a1 = 0.f, a2 = 0.f, a3 = 0.f;
        float a4 = 0.f, a5 = 0.f, a6 = 0.f, a7 = 0.f;
#pragma unroll
        for (int j = 0; j < 64; ++j) {
            const float p = sc[j];
            const float4 va = *(const float4*)(&Vs[col0 + j][d8 * 8]);
            const float4 vb = *(const float4*)(&Vs[col0 + j][d8 * 8 + 4]);
            a0 += p * va.x; a1 += p * va.y; a2 += p * va.z; a3 += p * va.w;
            a4 += p * vb.x; a5 += p * vb.y; a6 += p * vb.z; a7 += p * vb.w;
        }
        a0 = (a0 + __shfl_xor(a0, 1)) * inv;
        a1 = (a1 + __shfl_xor(a1, 1)) * inv;
        a2 = (a2 + __shfl_xor(a2, 1)) * inv;
        a3 = (a3 + __shfl_xor(a3, 1)) * inv;
        a4 = (a4 + __shfl_xor(a4, 1)) * inv;
        a5 = (a5 + __shfl_xor(a5, 1)) * inv;
        a6 = (a6 + __shfl_xor(a6, 1)) * inv;
        a7 = (a7 + __shfl_xor(a7, 1)) * inv;
        if (hf == (d8 >> 2)) {
            uint4 w;
            w.x = (uint)f2bf(a0) | ((uint)f2bf(a1) << 16);
            w.y = (uint)f2bf(a2) | ((uint)f2bf(a3) << 16);
            w.z = (uint)f2bf(a4) | ((uint)f2bf(a5) << 16);
            w.w = (uint)f2bf(a6) | ((uint)f2bf(a7) << 16);
            *(uint4*)(o_tok + rowr * 1024 + h * 64 + d8 * 8) = w;
        }
    }
}

// ---------------------------------------------------------------------------
extern "C" void kernel_launch(void* const* d_in, const int* in_sizes, int n_in,
                              void* d_out, int out_size, void* d_ws, size_t ws_size,
                              hipStream_t stream)
{
    const float* x         = (const float*)d_in[0];
    const float* ge_inp_w  = (const float*)d_in[1];
    const float* dw_w      = (const float*)d_in[2];
    const float* dw_b      = (const float*)d_in[3];
    const float* ge_out_w  = (const float*)d_in[4];
    const float* q_w       = (const float*)d_in[5];
    const float* k_w       = (const float*)d_in[6];
    const float* v_w       = (const float*)d_in[7];
    const float* Aq        = (const float*)d_in[8];
    const float* Bq        = (const float*)d_in[9];
    const float* Ak        = (const float*)d_in[10];
    const float* Bk        = (const float*)d_in[11];
    const float* rand_gate = (const float*)d_in[12];
    const float* base_w    = (const float*)d_in[13];
    const float* rot       = (const float*)d_in[14];
    const float* o_w       = (const float*)d_in[16];
    const int*   salts     = (const int*)d_in[17];

    char* ws = (char*)d_ws;
    float*          zg       = (float*)(ws + 0);
    __hip_bfloat16* qgkg_bf  = (__hip_bfloat16*)(ws + 0);
    __hip_bfloat16* xo_bf    = (__hip_bfloat16*)(ws + 33554432);
    __hip_bfloat16* Bt_geout = (__hip_bfloat16*)(ws + 50331648);
    __hip_bfloat16* Bt_q     = (__hip_bfloat16*)(ws + 54525952);
    __hip_bfloat16* Bt_k     = (__hip_bfloat16*)(ws + 56623104);
    __hip_bfloat16* Bt_v     = (__hip_bfloat16*)(ws + 57147392);
    __hip_bfloat16* Bt_o     = (__hip_bfloat16*)(ws + 57671680);
    ushort*         A0p      = (ushort*)(ws + 67108864);
    ushort*         A1p      = (ushort*)(ws + 83886080);
    float*          zm       = (float*)(ws + 67108864);
    float*          q0       = (float*)(ws + 67108864);
    ushort*         B0tp     = (ushort*)(ws + 100663296);
    ushort*         B1tp     = (ushort*)(ws + 104857600);
    __hip_bfloat16* zm_bf    = (__hip_bfloat16*)(ws + 100663296);
    float*          k0       = (float*)(ws + 100663296);
    float*          v0       = (float*)(ws + 109051904);
    float*          ktm      = (float*)(ws + 117440512);
    float*          Mq       = (float*)(ws + 125829120);
    float*          Mkf      = (float*)(ws + 125845504);
    double*         Wb       = (double*)(ws + 125861888);
    int*            bids     = (int*)(ws + 125927424);
    int*            order    = (int*)(ws + 125960192);
    int*            flagcnt  = (int*)(ws + 125992960);
    int*            flagged  = (int*)(ws + 125993216);
    float*          outp     = (float*)d_out;

    // Precomputes
    init_flag_kernel<<<1, 1, 0, stream>>>(flagcnt);
    lowrank_kernel<<<1, 256, 0, stream>>>(Aq, Bq, Ak, Bk, rand_gate, Mq, Mkf);
    wb_kernel<<<32, 256, 0, stream>>>(ge_out_w, base_w, Wb);
    split_a_kernel<<<8192, 256, 0, stream>>>((const float4*)x, (ushort4*)A0p, (ushort4*)A1p);
    split_bt2_kernel<<<dim3(64, 32), 256, 0, stream>>>(ge_inp_w, B0tp, B1tp);

    // GEMM1 (2-plane bf16-split MFMA): zg = x @ ge_inp_w  [8192x2048]
    gemm1_mfma2<<<dim3(16, 64), 256, 0, stream>>>(A0p, A1p, B0tp, B1tp, zg);
    // conv + silu*silu -> zm fp32 (over A0/A1) + zm_bf (over B0t/B1t)
    conv_silu_kernel<<<32768, 256, 0, stream>>>(zg, dw_w, dw_b, zm, zm_bf);

    // Casts / weight transposes (zg dead now)
    cast_bf16_kernel<<<8192, 256, 0, stream>>>((const float4*)x, (ushort4*)xo_bf);
    transpose_cast_kernel<<<dim3(64, 32), 256, 0, stream>>>(ge_out_w, Bt_geout, 1024, 2048);
    transpose_cast_kernel<<<dim3(32, 32), 256, 0, stream>>>(q_w, Bt_q, 1024, 1024);
    transpose_cast_kernel<<<dim3(8, 32), 256, 0, stream>>>(k_w, Bt_k, 1024, 256);
    transpose_cast_kernel<<<dim3(8, 32), 256, 0, stream>>>(v_w, Bt_v, 1024, 256);
    transpose_cast_kernel<<<dim3(32, 32), 256, 0, stream>>>(o_w, Bt_o, 1024, 1024);

    // GEMM2 (bf16 MFMA): qgkg_bf = zm_bf @ ge_out_w  [8192x2048]
    gemm_mfma_bt<__hip_bfloat16><<<dim3(16, 64), 256, 0, stream>>>(
        (const ushort*)zm_bf, 1024, (const ushort*)Bt_geout, qgkg_bf, 2048, 1024);

    // hash + flag -> bids; exact fixup for near-zero sims; stable sort
    hash_flag_kernel<<<2048, 256, 0, stream>>>(zm, Wb, rot, salts, bids, flagcnt, flagged);
    fixup_kernel<<<MAXFLAG, 512, 0, stream>>>(x, ge_inp_w, dw_w, dw_b, Wb, rot, salts,
                                              flagcnt, flagged, bids);
    sort_kernel<<<2, 256, 0, stream>>>(bids, order);

    // q0 = qg @ q_w [8192x1024] (overwrites zm; hash done)
    gemm_mfma_bt<float><<<dim3(8, 64), 256, 0, stream>>>(
        (const ushort*)qgkg_bf, 2048, (const ushort*)Bt_q, q0, 1024, 1024);
    rowmat64_kernel<<<2048, 256, 0, stream>>>(q0, Mq);

    // k0 = kg @ k_w [8192x256] (overwrites zm_bf; GEMM2 + fixup done)
    gemm_mfma_bt<float><<<dim3(2, 64), 256, 0, stream>>>(
        (const ushort*)(qgkg_bf + 1024), 2048, (const ushort*)Bt_k, k0, 256, 1024);
    rowmat64_kernel<<<512, 256, 0, stream>>>(k0, Mkf);
    pairmix_kernel<<<8192, 256, 0, stream>>>(k0, ktm);

    // v0 = x @ v_w [8192x256]
    gemm_mfma_bt<float><<<dim3(2, 64), 256, 0, stream>>>(
        (const ushort*)xo_bf, 1024, (const ushort*)Bt_v, v0, 256, 1024);

    // bucketed attention -> o_bf (overwrites x_bf); c-fastest grid (R4 layout)
    attn_kernel<<<dim3(32, 16, 2), 256, 0, stream>>>(q0, ktm, v0, order, xo_bf);

    // final: out = o @ o_w [8192x1024]
    gemm_mfma_bt<float><<<dim3(8, 64), 256, 0, stream>>>(
        (const ushort*)xo_bf, 1024, (const ushort*)Bt_o, outp, 1024, 1024);
}